// Round 2
// baseline (2119.534 us; speedup 1.0000x reference)
//
#include <hip/hip_runtime.h>

#define SLOTS 7
#define BATCH 8192
#define DIN 1024
#define EDIM 256
#define HDIM 512
#define SHDIM 256
#define VDIM 100

typedef __attribute__((ext_vector_type(8))) __bf16 bf16x8;
typedef __attribute__((ext_vector_type(4))) float f32x4;

__device__ __forceinline__ void gl_lds16(const __bf16* g, __bf16* l) {
  __builtin_amdgcn_global_load_lds(
      (const __attribute__((address_space(1))) void*)g,
      (__attribute__((address_space(3))) void*)l, 16, 0, 0);
}

__device__ __forceinline__ float sigmoidf_(float x) {
  return 1.f / (1.f + __expf(-x));
}

// ---------------------------------------------------------------------------
// GEMM: C[M,N] = A[M,K] (bf16, lda) @ Bw[N,K]^T (bf16, ldb)
// MODE 0: fp32 store plain           MODE 1: bf16 store, bias + relu
// MODE 2: fp32 store, bias, col<Nreal bound   MODE 3: fp32 accumulate (C +=)
// 128x128 tile, BK=32, 4 waves (2x2 of 64x64), mfma_f32_16x16x32_bf16.
// ---------------------------------------------------------------------------
template <int MODE>
__global__ void __launch_bounds__(256)
gemm_bt(const __bf16* __restrict__ A, int lda,
        const __bf16* __restrict__ Bw, int ldb,
        void* __restrict__ Cout, int ldc,
        const float* __restrict__ bias,
        int M, int N, int K, int Nreal) {
  __shared__ __align__(16) __bf16 As[2][128 * 32];
  __shared__ __align__(16) __bf16 Bs[2][128 * 32];
  const int w = threadIdx.x >> 6;
  const int lane = threadIdx.x & 63;
  const int wr = w >> 1, wc = w & 1;
  const int rowBase = blockIdx.y << 7;
  const int colBase = blockIdx.x << 7;
  const int sr = lane >> 2;         // row within 16-row staging group
  const int sc = (lane & 3) << 3;   // k element offset (8 bf16 = 16B)

  f32x4 acc[4][4];
#pragma unroll
  for (int i = 0; i < 4; ++i)
#pragma unroll
    for (int j = 0; j < 4; ++j) acc[i][j] = (f32x4){0.f, 0.f, 0.f, 0.f};

  const int nsteps = K >> 5;

#define STAGE(bi, k0)                                                           \
  {                                                                             \
    const __bf16* ga = A + (size_t)(rowBase + (w << 5) + sr) * lda + (k0) + sc; \
    gl_lds16(ga, &As[(bi)][(w << 5) * 32]);                                     \
    gl_lds16(ga + (size_t)16 * lda, &As[(bi)][((w << 5) + 16) * 32]);           \
    const __bf16* gb = Bw + (size_t)(colBase + (w << 5) + sr) * ldb + (k0) + sc;\
    gl_lds16(gb, &Bs[(bi)][(w << 5) * 32]);                                     \
    gl_lds16(gb + (size_t)16 * ldb, &Bs[(bi)][((w << 5) + 16) * 32]);           \
  }

  STAGE(0, 0);
  __syncthreads();
  int buf = 0;
  const int ln = lane & 15;
  const int kg = (lane >> 4) << 3;
  for (int t = 0; t < nsteps; ++t) {
    if (t + 1 < nsteps) STAGE(buf ^ 1, (t + 1) << 5);
    bf16x8 av[4], bv[4];
#pragma unroll
    for (int i = 0; i < 4; ++i)
      av[i] = *(const bf16x8*)&As[buf][((wr << 6) + (i << 4) + ln) * 32 + kg];
#pragma unroll
    for (int i = 0; i < 4; ++i)
      bv[i] = *(const bf16x8*)&Bs[buf][((wc << 6) + (i << 4) + ln) * 32 + kg];
#pragma unroll
    for (int mi = 0; mi < 4; ++mi)
#pragma unroll
      for (int ni = 0; ni < 4; ++ni)
        acc[mi][ni] = __builtin_amdgcn_mfma_f32_16x16x32_bf16(
            av[mi], bv[ni], acc[mi][ni], 0, 0, 0);
    __syncthreads();
    buf ^= 1;
  }
#undef STAGE

  // epilogue: C/D layout col=lane&15, row=(lane>>4)*4+reg  [m89/m91-verified]
  const int lh = lane >> 4;
  const int row0 = rowBase + (wr << 6) + (lh << 2);
  const int col0 = colBase + (wc << 6) + ln;
  if (MODE == 0) {
    float* C = (float*)Cout;
#pragma unroll
    for (int mi = 0; mi < 4; ++mi)
#pragma unroll
      for (int ni = 0; ni < 4; ++ni) {
        const int col = col0 + (ni << 4);
#pragma unroll
        for (int r = 0; r < 4; ++r)
          C[(size_t)(row0 + (mi << 4) + r) * ldc + col] = acc[mi][ni][r];
      }
  } else if (MODE == 1) {
    __bf16* C = (__bf16*)Cout;
#pragma unroll
    for (int mi = 0; mi < 4; ++mi)
#pragma unroll
      for (int ni = 0; ni < 4; ++ni) {
        const int col = col0 + (ni << 4);
        const float b = bias[col];
#pragma unroll
        for (int r = 0; r < 4; ++r) {
          float v = acc[mi][ni][r] + b;
          v = fmaxf(v, 0.f);
          C[(size_t)(row0 + (mi << 4) + r) * ldc + col] = (__bf16)v;
        }
      }
  } else if (MODE == 2) {
    float* C = (float*)Cout;
#pragma unroll
    for (int mi = 0; mi < 4; ++mi)
#pragma unroll
      for (int ni = 0; ni < 4; ++ni) {
        const int col = col0 + (ni << 4);
        if (col < Nreal) {
          const float b = bias[col];
#pragma unroll
          for (int r = 0; r < 4; ++r)
            C[(size_t)(row0 + (mi << 4) + r) * ldc + col] = acc[mi][ni][r] + b;
        }
      }
  } else {  // MODE 3: accumulate
    float* C = (float*)Cout;
#pragma unroll
    for (int mi = 0; mi < 4; ++mi)
#pragma unroll
      for (int ni = 0; ni < 4; ++ni) {
        const int col = col0 + (ni << 4);
#pragma unroll
        for (int r = 0; r < 4; ++r)
          C[(size_t)(row0 + (mi << 4) + r) * ldc + col] += acc[mi][ni][r];
      }
  }
}

// ---------------------------------------------------------------------------
// Weight pack (single slot): fp32 -> bf16, zero-pad beyond src extents.
// dst[dOff + r*dLd + c] = (r<rows_s && c<cols_s) ? src[r*sLd + c] : 0
// ---------------------------------------------------------------------------
__global__ void pack_w(const float* __restrict__ src, __bf16* __restrict__ dst,
                       int cols, int rows_s, int cols_s,
                       int sLd, int dLd, long dOff, int total) {
  int idx = blockIdx.x * 256 + threadIdx.x;
  if (idx >= total) return;
  int r = idx / cols;
  int c = idx - r * cols;
  float v = (r < rows_s && c < cols_s) ? src[(long)r * sLd + c] : 0.f;
  dst[dOff + (long)r * dLd + c] = (__bf16)v;
}

__global__ void conv_inputs(const float* __restrict__ in, __bf16* __restrict__ xh) {
  int idx = blockIdx.x * 256 + threadIdx.x;  // B*1024
  int b = idx >> 10, c = idx & 1023;
  xh[(size_t)b * 1792 + c] = (__bf16)in[idx];
}

__global__ void set_start(const float* __restrict__ start, __bf16* __restrict__ xh) {
  int idx = blockIdx.x * 256 + threadIdx.x;  // B*256
  int b = idx >> 8, e = idx & 255;
  xh[(size_t)b * 1792 + 1024 + e] = (__bf16)start[e];
}

__global__ void emb_gather(const float* __restrict__ emb, const int* __restrict__ labels,
                           __bf16* __restrict__ xh) {
  int idx = blockIdx.x * 256 + threadIdx.x;  // B*256
  int b = idx >> 8, e = idx & 255;
  int lab = labels[b];
  xh[(size_t)b * 1792 + 1024 + e] = (__bf16)emb[(size_t)lab * 256 + e];
}

__global__ void zero_states(__bf16* __restrict__ xh, __bf16* __restrict__ xh1) {
  int idx = blockIdx.x * 256 + threadIdx.x;  // B*512
  int b = idx >> 9, h = idx & 511;
  xh[(size_t)b * 1792 + 1280 + h] = (__bf16)0.f;
  xh1[(size_t)b * 1024 + 512 + h] = (__bf16)0.f;
}

// LSTM cell elementwise: gates (pre-bias) -> h (bf16 into hout), c updated.
__global__ void ew_lstm(const float* __restrict__ gates, int ldg,
                        const float* __restrict__ b_ih, const float* __restrict__ b_hh,
                        float* __restrict__ cst, __bf16* __restrict__ hout,
                        int hld, int hoff) {
  int idx = blockIdx.x * 256 + threadIdx.x;  // B*512
  int b = idx >> 9, h = idx & 511;
  const float* g = gates + (size_t)b * ldg;
  float gi = g[h] + b_ih[h] + b_hh[h];
  float gf = g[512 + h] + b_ih[512 + h] + b_hh[512 + h];
  float gg = g[1024 + h] + b_ih[1024 + h] + b_hh[1024 + h];
  float go = g[1536 + h] + b_ih[1536 + h] + b_hh[1536 + h];
  float ii = sigmoidf_(gi);
  float ff = sigmoidf_(gf);
  float gt = tanhf(gg);
  float oo = sigmoidf_(go);
  float c = ff * cst[idx] + ii * gt;
  cst[idx] = c;
  hout[(size_t)b * hld + hoff + h] = (__bf16)(oo * tanhf(c));
}

// Highway combine: gateN = sig(gates[2048+h] + b); cur = gateN*h0 + (1-gateN)*hwL
__global__ void ew_hwy(const float* __restrict__ gates, const float* __restrict__ hwNb,
                       const __bf16* __restrict__ xh, __bf16* __restrict__ xh1) {
  int idx = blockIdx.x * 256 + threadIdx.x;  // B*512
  int b = idx >> 9, h = idx & 511;
  const float* g = gates + (size_t)b * 3072;
  float hn = (float)xh[(size_t)b * 1792 + 1280 + h];
  float gn = sigmoidf_(g[2048 + h] + hwNb[h]);
  float cur = gn * hn + (1.f - gn) * g[2560 + h];
  xh1[(size_t)b * 1024 + h] = (__bf16)cur;
}

extern "C" void kernel_launch(void* const* d_in, const int* in_sizes, int n_in,
                              void* d_out, int out_size, void* d_ws, size_t ws_size,
                              hipStream_t stream) {
  const float* inputs = (const float*)d_in[0];
  const int* labels = (const int*)d_in[1];
  const float* start = (const float*)d_in[2];
  const float* emb = (const float*)d_in[3];
  const float* W_ih0 = (const float*)d_in[4];
  const float* W_hh0 = (const float*)d_in[5];
  const float* b_ih0 = (const float*)d_in[6];
  const float* b_hh0 = (const float*)d_in[7];
  const float* hwN_W0 = (const float*)d_in[8];
  const float* hwN_b0 = (const float*)d_in[9];
  const float* hwL_W0 = (const float*)d_in[10];
  const float* W_ih1 = (const float*)d_in[11];
  const float* W_hh1 = (const float*)d_in[12];
  const float* b_ih1 = (const float*)d_in[13];
  const float* b_hh1 = (const float*)d_in[14];
  // d_in[15..17]: hwN_W1 / hwN_b1 / hwL_W1 — dead in reference, skipped
  const float* sh_W = (const float*)d_in[18];
  const float* sh_b = (const float*)d_in[19];
  const float* pred_W = (const float*)d_in[20];
  const float* pred_b = (const float*)d_in[21];
  float* out = (float*)d_out;

  char* p = (char*)d_ws;
  size_t off = 0;
  auto alloc = [&](size_t bytes) {
    void* r = p + off;
    off += (bytes + 255) & ~(size_t)255;
    return r;
  };
  // single-slot packed bf16 weight buffers (repacked each slot; ~16 MB)
  __bf16* WA = (__bf16*)alloc((size_t)3072 * 1792 * 2);  // [Wih0|Whh0; hwNx|0; hwL|0]
  __bf16* WH = (__bf16*)alloc((size_t)512 * 512 * 2);    // hwN h-part
  __bf16* WB = (__bf16*)alloc((size_t)2048 * 1024 * 2);  // [Wih1|Whh1]
  __bf16* WS = (__bf16*)alloc((size_t)256 * 512 * 2);    // sh_W
  __bf16* WP = (__bf16*)alloc((size_t)128 * 256 * 2);    // pred_W padded to 128 rows
  // activations
  __bf16* xh = (__bf16*)alloc((size_t)BATCH * 1792 * 2);   // [inputs | emb | h0]
  __bf16* xh1 = (__bf16*)alloc((size_t)BATCH * 1024 * 2);  // [cur | h1]
  float* gates = (float*)alloc((size_t)BATCH * 3072 * 4);
  float* c0 = (float*)alloc((size_t)BATCH * 512 * 4);
  float* c1 = (float*)alloc((size_t)BATCH * 512 * 4);
  // hidden (bf16, 4.2MB) aliases the head of gates: gates is dead between
  // layer-1 ew_lstm (its last reader) and next slot's GEMM0 (full overwrite).
  __bf16* hidden = (__bf16*)gates;
  (void)ws_size; (void)in_sizes; (void)n_in; (void)out_size;

  hipMemsetAsync(c0, 0, (size_t)BATCH * 512 * 4, stream);
  hipMemsetAsync(c1, 0, (size_t)BATCH * 512 * 4, stream);
  zero_states<<<BATCH * 512 / 256, 256, 0, stream>>>(xh, xh1);
  conv_inputs<<<BATCH * 1024 / 256, 256, 0, stream>>>(inputs, xh);
  set_start<<<BATCH * 256 / 256, 256, 0, stream>>>(start, xh);

  const dim3 blk(256);
  for (int s = 0; s < SLOTS; ++s) {
    // ---- pack this slot's weights (stream-serial; ~16 MB) ----
    {
      int t;
      // W_ih0 -> WA rows 0:2048, cols 0:1280
      t = 2048 * 1280;
      pack_w<<<(t + 255) / 256, blk, 0, stream>>>(
          W_ih0 + (size_t)s * 2048 * 1280, WA, 1280, 2048, 1280, 1280, 1792, 0, t);
      // W_hh0 -> WA rows 0:2048, cols 1280:1792
      t = 2048 * 512;
      pack_w<<<(t + 255) / 256, blk, 0, stream>>>(
          W_hh0 + (size_t)s * 2048 * 512, WA, 512, 2048, 512, 512, 1792, 1280, t);
      // hwN_W0 x-part -> WA rows 2048:2560, cols 0:1280, zero-pad 1280:1792
      t = 512 * 1792;
      pack_w<<<(t + 255) / 256, blk, 0, stream>>>(
          hwN_W0 + (size_t)s * 512 * 1792, WA, 1792, 512, 1280, 1792, 1792,
          (long)2048 * 1792, t);
      // hwL_W0 -> WA rows 2560:3072, cols 0:1280, zero-pad 1280:1792
      pack_w<<<(t + 255) / 256, blk, 0, stream>>>(
          hwL_W0 + (size_t)s * 512 * 1280, WA, 1792, 512, 1280, 1280, 1792,
          (long)2560 * 1792, t);
      // hwN_W0 h-part (src cols 1280:1792) -> WH [512,512]
      t = 512 * 512;
      pack_w<<<(t + 255) / 256, blk, 0, stream>>>(
          hwN_W0 + (size_t)s * 512 * 1792 + 1280, WH, 512, 512, 512, 1792, 512, 0, t);
      // W_ih1 -> WB cols 0:512
      t = 2048 * 512;
      pack_w<<<(t + 255) / 256, blk, 0, stream>>>(
          W_ih1 + (size_t)s * 2048 * 512, WB, 512, 2048, 512, 512, 1024, 0, t);
      // W_hh1 -> WB cols 512:1024
      pack_w<<<(t + 255) / 256, blk, 0, stream>>>(
          W_hh1 + (size_t)s * 2048 * 512, WB, 512, 2048, 512, 512, 1024, 512, t);
      // sh_W -> WS
      t = 256 * 512;
      pack_w<<<(t + 255) / 256, blk, 0, stream>>>(
          sh_W + (size_t)s * 256 * 512, WS, 512, 256, 512, 512, 512, 0, t);
      // pred_W -> WP (pad rows 100:128 with zeros)
      t = 128 * 256;
      pack_w<<<(t + 255) / 256, blk, 0, stream>>>(
          pred_W + (size_t)s * 100 * 256, WP, 256, 100, 256, 256, 256, 0, t);
    }

    // GEMM0: gates[:,0:2048]=lstm pre-acts, [2048:2560]=hwN x-part, [2560:3072]=hwL
    gemm_bt<0><<<dim3(24, 64), blk, 0, stream>>>(
        xh, 1792, WA, 1792, gates, 3072, nullptr, BATCH, 3072, 1792, 3072);
    // layer-0 LSTM cell -> h0 (bf16 into xh[:,1280:1792]), c0
    ew_lstm<<<BATCH * 512 / 256, blk, 0, stream>>>(
        gates, 3072, b_ih0 + s * 2048, b_hh0 + s * 2048, c0, xh, 1792, 1280);
    // hwN h-part with NEW h0: gates[:,2048:2560] += h0_new @ WH^T
    gemm_bt<3><<<dim3(4, 64), blk, 0, stream>>>(
        xh + 1280, 1792, WH, 512, gates + 2048, 3072, nullptr, BATCH, 512, 512, 512);
    // highway combine -> cur (bf16 into xh1[:,0:512])
    ew_hwy<<<BATCH * 512 / 256, blk, 0, stream>>>(gates, hwN_b0 + s * 512, xh, xh1);
    // teacher-forced embedding for next slot (after GEMM0 consumed current emb)
    if (s < SLOTS - 1)
      emb_gather<<<BATCH * 256 / 256, blk, 0, stream>>>(
          emb + (size_t)s * VDIM * EDIM, labels + (size_t)s * BATCH, xh);
    // GEMM1: gates[:,0:2048] = [cur|h1] @ [Wih1|Whh1]^T
    gemm_bt<0><<<dim3(16, 64), blk, 0, stream>>>(
        xh1, 1024, WB, 1024, gates, 2048, nullptr, BATCH, 2048, 1024, 2048);
    // layer-1 LSTM cell -> h1 (bf16 into xh1[:,512:1024]), c1
    ew_lstm<<<BATCH * 512 / 256, blk, 0, stream>>>(
        gates, 2048, b_ih1 + s * 2048, b_hh1 + s * 2048, c1, xh1, 1024, 512);
    // sh: hidden = relu(h1 @ sh_W^T + sh_b), bf16  (hidden aliases gates head;
    // gates is fully dead here — last read was ew_lstm above)
    gemm_bt<1><<<dim3(2, 64), blk, 0, stream>>>(
        xh1 + 512, 1024, WS, 512, hidden, 256, sh_b + s * 256, BATCH, 256, 512, 256);
    // pred: logits = hidden @ pred_W^T + pred_b -> d_out[s]
    gemm_bt<2><<<dim3(1, 64), blk, 0, stream>>>(
        hidden, 256, WP, 256, out + (size_t)s * BATCH * VDIM, VDIM,
        pred_b + s * VDIM, BATCH, 128, 256, VDIM);
  }
}

// Round 3
// 1961.440 us; speedup vs baseline: 1.0806x; 1.0806x over previous
//
#include <hip/hip_runtime.h>

#define SLOTS 7
#define BATCH 8192
#define HDIM 512

typedef __attribute__((ext_vector_type(8))) __bf16 bf16x8;
typedef __attribute__((ext_vector_type(4))) float f32x4;

__device__ __forceinline__ void gl_lds16(const __bf16* g, __bf16* l) {
  __builtin_amdgcn_global_load_lds(
      (const __attribute__((address_space(1))) void*)g,
      (__attribute__((address_space(3))) void*)l, 16, 0, 0);
}

__device__ __forceinline__ float sigmoidf_(float x) {
  return 1.f / (1.f + __expf(-x));
}
__device__ __forceinline__ float tanhf_(float x) {
  float xc = fminf(fmaxf(x, -15.f), 15.f);
  float e = __expf(2.f * xc);
  return (e - 1.f) / (e + 1.f);
}

// ---------------------------------------------------------------------------
// GEMM: C[M,N] = A[M,K] (bf16, lda) @ Bw[N,K]^T (bf16, ldb), fused epilogues.
// MODE 1: bf16 store, bias + relu                    (sh layer)
// MODE 2: fp32 store, bias, col<Nreal bound          (pred layer)
// MODE 4: LSTM cell epilogue on gate-interleaved cols < Nreal;
//         cols >= Nreal stored fp32 to auxw (ld 1024, col-Nreal offset)
// MODE 6: highway epilogue: sig(acc + aux_x + bias)*hn + (1-g)*aux_l
// 128x128 tile, BK=32, 4 waves (2x2 of 64x64), mfma_f32_16x16x32_bf16.
// ---------------------------------------------------------------------------
template <int MODE>
__global__ void __launch_bounds__(256)
gemm_bt(const __bf16* __restrict__ A, int lda,
        const __bf16* __restrict__ Bw, int ldb,
        void* __restrict__ Cout, int ldc,
        const float* __restrict__ bias, const float* __restrict__ bias2,
        float* __restrict__ cst, __bf16* __restrict__ hout, int hld, int hoff,
        const float* __restrict__ auxr, float* __restrict__ auxw,
        const __bf16* __restrict__ hsrc,
        int M, int N, int K, int Nreal) {
  __shared__ __align__(16) __bf16 As[2][128 * 32];
  __shared__ __align__(16) __bf16 Bs[2][128 * 32];
  const int w = threadIdx.x >> 6;
  const int lane = threadIdx.x & 63;
  const int wr = w >> 1, wc = w & 1;
  const int rowBase = blockIdx.y << 7;
  const int colBase = blockIdx.x << 7;
  const int sr = lane >> 2;        // row within 16-row staging group
  const int sc = (lane & 3) << 3;  // k element offset (8 bf16 = 16B)

  f32x4 acc[4][4];
#pragma unroll
  for (int i = 0; i < 4; ++i)
#pragma unroll
    for (int j = 0; j < 4; ++j) acc[i][j] = (f32x4){0.f, 0.f, 0.f, 0.f};

  const int nsteps = K >> 5;

#define STAGE(bi, k0)                                                           \
  {                                                                             \
    const __bf16* ga = A + (size_t)(rowBase + (w << 5) + sr) * lda + (k0) + sc; \
    gl_lds16(ga, &As[(bi)][(w << 5) * 32]);                                     \
    gl_lds16(ga + (size_t)16 * lda, &As[(bi)][((w << 5) + 16) * 32]);           \
    const __bf16* gb = Bw + (size_t)(colBase + (w << 5) + sr) * ldb + (k0) + sc;\
    gl_lds16(gb, &Bs[(bi)][(w << 5) * 32]);                                     \
    gl_lds16(gb + (size_t)16 * ldb, &Bs[(bi)][((w << 5) + 16) * 32]);           \
  }

  STAGE(0, 0);
  __syncthreads();
  int buf = 0;
  const int ln = lane & 15;
  const int kg = (lane >> 4) << 3;
  for (int t = 0; t < nsteps; ++t) {
    if (t + 1 < nsteps) STAGE(buf ^ 1, (t + 1) << 5);
    bf16x8 av[4], bv[4];
#pragma unroll
    for (int i = 0; i < 4; ++i)
      av[i] = *(const bf16x8*)&As[buf][((wr << 6) + (i << 4) + ln) * 32 + kg];
#pragma unroll
    for (int i = 0; i < 4; ++i)
      bv[i] = *(const bf16x8*)&Bs[buf][((wc << 6) + (i << 4) + ln) * 32 + kg];
#pragma unroll
    for (int mi = 0; mi < 4; ++mi)
#pragma unroll
      for (int ni = 0; ni < 4; ++ni)
        acc[mi][ni] = __builtin_amdgcn_mfma_f32_16x16x32_bf16(
            av[mi], bv[ni], acc[mi][ni], 0, 0, 0);
    __syncthreads();
    buf ^= 1;
  }
#undef STAGE

  // epilogue: C/D layout col=lane&15, row=(lane>>4)*4+reg  [m89/m91-verified]
  const int lh = lane >> 4;
  const int row0 = rowBase + (wr << 6) + (lh << 2);
  const int col0 = colBase + (wc << 6) + ln;

  if (MODE == 1) {  // bf16, bias + relu
    __bf16* C = (__bf16*)Cout;
#pragma unroll
    for (int mi = 0; mi < 4; ++mi)
#pragma unroll
      for (int ni = 0; ni < 4; ++ni) {
        const int col = col0 + (ni << 4);
        const float b = bias[col];
#pragma unroll
        for (int r = 0; r < 4; ++r) {
          float v = fmaxf(acc[mi][ni][r] + b, 0.f);
          C[(size_t)(row0 + (mi << 4) + r) * ldc + col] = (__bf16)v;
        }
      }
  } else if (MODE == 2) {  // fp32, bias, bounded cols
    float* C = (float*)Cout;
#pragma unroll
    for (int mi = 0; mi < 4; ++mi)
#pragma unroll
      for (int ni = 0; ni < 4; ++ni) {
        const int col = col0 + (ni << 4);
        if (col < Nreal) {
          const float b = bias[col];
#pragma unroll
          for (int r = 0; r < 4; ++r)
            C[(size_t)(row0 + (mi << 4) + r) * ldc + col] = acc[mi][ni][r] + b;
        }
      }
  } else if (MODE == 4) {  // LSTM cell (gate-interleaved) / aux fp32 store
    if (colBase < Nreal) {
      // lane's unit: h = (colBase/64 + wc)*16 + ln ; gate g = ni
      const int h = (((colBase >> 6) + wc) << 4) + ln;
      float bs0 = bias[h] + bias2[h];
      float bs1 = bias[512 + h] + bias2[512 + h];
      float bs2 = bias[1024 + h] + bias2[1024 + h];
      float bs3 = bias[1536 + h] + bias2[1536 + h];
#pragma unroll
      for (int mi = 0; mi < 4; ++mi)
#pragma unroll
        for (int r = 0; r < 4; ++r) {
          const int row = row0 + (mi << 4) + r;
          float gi = sigmoidf_(acc[mi][0][r] + bs0);
          float gf = sigmoidf_(acc[mi][1][r] + bs1);
          float gg = tanhf_(acc[mi][2][r] + bs2);
          float go = sigmoidf_(acc[mi][3][r] + bs3);
          const size_t ci = (size_t)row * 512 + h;
          float cn = gf * cst[ci] + gi * gg;
          cst[ci] = cn;
          hout[(size_t)row * hld + hoff + h] = (__bf16)(go * tanhf_(cn));
        }
    } else {
#pragma unroll
      for (int mi = 0; mi < 4; ++mi)
#pragma unroll
        for (int ni = 0; ni < 4; ++ni) {
          const int col = col0 + (ni << 4) - Nreal;
#pragma unroll
          for (int r = 0; r < 4; ++r)
            auxw[(size_t)(row0 + (mi << 4) + r) * 1024 + col] = acc[mi][ni][r];
        }
    }
  } else if (MODE == 6) {  // highway combine
    __bf16* C = (__bf16*)Cout;
#pragma unroll
    for (int mi = 0; mi < 4; ++mi)
#pragma unroll
      for (int ni = 0; ni < 4; ++ni) {
        const int col = col0 + (ni << 4);
#pragma unroll
        for (int r = 0; r < 4; ++r) {
          const int row = row0 + (mi << 4) + r;
          float xp = auxr[(size_t)row * 1024 + col];
          float hwl = auxr[(size_t)row * 1024 + 512 + col];
          float gn = sigmoidf_(acc[mi][ni][r] + xp + bias[col]);
          float hn = (float)hsrc[(size_t)row * 512 + col];
          C[(size_t)row * ldc + col] = (__bf16)(gn * hn + (1.f - gn) * hwl);
          hout[(size_t)row * hld + hoff + col] = (__bf16)hn;  // h0 -> xh
        }
      }
  }
}

// ---------------------------------------------------------------------------
// Weight pack kernels (single slot): fp32 -> bf16.
// ---------------------------------------------------------------------------
__global__ void pack_w(const float* __restrict__ src, __bf16* __restrict__ dst,
                       int cols, int rows_s, int cols_s,
                       int sLd, int dLd, long dOff, int total) {
  int idx = blockIdx.x * 256 + threadIdx.x;
  if (idx >= total) return;
  int r = idx / cols;
  int c = idx - r * cols;
  float v = (r < rows_s && c < cols_s) ? src[(long)r * sLd + c] : 0.f;
  dst[dOff + (long)r * dLd + c] = (__bf16)v;
}

// gate-interleaved pack: dst row r <- src row ((r>>4)&3)*512 + (r>>6)*16 + (r&15)
__global__ void pack_perm(const float* __restrict__ src, __bf16* __restrict__ dst,
                          int cols, int sLd, int dLd, long dColOff, int total) {
  int idx = blockIdx.x * 256 + threadIdx.x;
  if (idx >= total) return;
  int r = idx / cols;
  int c = idx - r * cols;
  int srcr = (((r >> 4) & 3) << 9) + ((r >> 6) << 4) + (r & 15);
  dst[(long)r * dLd + dColOff + c] = (__bf16)src[(long)srcr * sLd + c];
}

__global__ void conv_inputs(const float* __restrict__ in, __bf16* __restrict__ xh) {
  int idx = blockIdx.x * 256 + threadIdx.x;  // B*1024
  int b = idx >> 10, c = idx & 1023;
  xh[(size_t)b * 1792 + c] = (__bf16)in[idx];
}

__global__ void set_start(const float* __restrict__ start, __bf16* __restrict__ xh) {
  int idx = blockIdx.x * 256 + threadIdx.x;  // B*256
  int b = idx >> 8, e = idx & 255;
  xh[(size_t)b * 1792 + 1024 + e] = (__bf16)start[e];
}

__global__ void emb_gather(const float* __restrict__ emb, const int* __restrict__ labels,
                           __bf16* __restrict__ xh) {
  int idx = blockIdx.x * 256 + threadIdx.x;  // B*256
  int b = idx >> 8, e = idx & 255;
  int lab = labels[b];
  xh[(size_t)b * 1792 + 1024 + e] = (__bf16)emb[(size_t)lab * 256 + e];
}

__global__ void zero_states(__bf16* __restrict__ xh, __bf16* __restrict__ xh1A) {
  int idx = blockIdx.x * 256 + threadIdx.x;  // B*512
  int b = idx >> 9, h = idx & 511;
  xh[(size_t)b * 1792 + 1280 + h] = (__bf16)0.f;   // h0 = 0
  xh1A[(size_t)b * 1024 + 512 + h] = (__bf16)0.f;  // h1 = 0 (buffer 0)
}

extern "C" void kernel_launch(void* const* d_in, const int* in_sizes, int n_in,
                              void* d_out, int out_size, void* d_ws, size_t ws_size,
                              hipStream_t stream) {
  const float* inputs = (const float*)d_in[0];
  const int* labels = (const int*)d_in[1];
  const float* start = (const float*)d_in[2];
  const float* emb = (const float*)d_in[3];
  const float* W_ih0 = (const float*)d_in[4];
  const float* W_hh0 = (const float*)d_in[5];
  const float* b_ih0 = (const float*)d_in[6];
  const float* b_hh0 = (const float*)d_in[7];
  const float* hwN_W0 = (const float*)d_in[8];
  const float* hwN_b0 = (const float*)d_in[9];
  const float* hwL_W0 = (const float*)d_in[10];
  const float* W_ih1 = (const float*)d_in[11];
  const float* W_hh1 = (const float*)d_in[12];
  const float* b_ih1 = (const float*)d_in[13];
  const float* b_hh1 = (const float*)d_in[14];
  // d_in[15..17]: hwN_W1 / hwN_b1 / hwL_W1 — dead in reference, skipped
  const float* sh_W = (const float*)d_in[18];
  const float* sh_b = (const float*)d_in[19];
  const float* pred_W = (const float*)d_in[20];
  const float* pred_b = (const float*)d_in[21];
  float* out = (float*)d_out;

  char* p = (char*)d_ws;
  size_t off = 0;
  auto alloc = [&](size_t bytes) {
    void* r = p + off;
    off += (bytes + 255) & ~(size_t)255;
    return r;
  };
  // single-slot packed bf16 weights (~16 MB)
  __bf16* WA = (__bf16*)alloc((size_t)3072 * 1792 * 2);  // [ih0|hh0 interleaved; hwNx|0; hwL|0]
  __bf16* WH = (__bf16*)alloc((size_t)512 * 512 * 2);    // hwN h-part
  __bf16* WB = (__bf16*)alloc((size_t)2048 * 1024 * 2);  // [ih1|hh1 interleaved]
  __bf16* WS = (__bf16*)alloc((size_t)256 * 512 * 2);    // sh_W
  __bf16* WP = (__bf16*)alloc((size_t)128 * 256 * 2);    // pred_W (rows padded to 128)
  // activations
  __bf16* xh = (__bf16*)alloc((size_t)BATCH * 1792 * 2);  // [inputs | emb | h0]
  __bf16* xh1A = (__bf16*)alloc((size_t)BATCH * 1024 * 2);  // ping-pong [cur | h1]
  __bf16* xh1B = (__bf16*)alloc((size_t)BATCH * 1024 * 2);
  __bf16* h0new = (__bf16*)alloc((size_t)BATCH * 512 * 2);
  float* ghw = (float*)alloc((size_t)BATCH * 1024 * 4);  // [hwN-x | hwL] fp32
  float* c0 = (float*)alloc((size_t)BATCH * 512 * 4);
  float* c1 = (float*)alloc((size_t)BATCH * 512 * 4);
  // hidden aliases ghw head: ghw dead after gemm_hwy; fully rewritten next slot
  __bf16* hidden = (__bf16*)ghw;
  (void)ws_size; (void)in_sizes; (void)n_in; (void)out_size;

  hipMemsetAsync(c0, 0, (size_t)BATCH * 512 * 4, stream);
  hipMemsetAsync(c1, 0, (size_t)BATCH * 512 * 4, stream);
  zero_states<<<BATCH * 512 / 256, 256, 0, stream>>>(xh, xh1A);
  conv_inputs<<<BATCH * 1024 / 256, 256, 0, stream>>>(inputs, xh);
  set_start<<<BATCH * 256 / 256, 256, 0, stream>>>(start, xh);

  const dim3 blk(256);
  for (int s = 0; s < SLOTS; ++s) {
    __bf16* xcur = (s & 1) ? xh1B : xh1A;   // GEMM1 input this slot
    __bf16* xnext = (s & 1) ? xh1A : xh1B;  // h1_new destination
    // ---- pack this slot's weights ----
    {
      int t;
      // W_ih0 (gate-interleaved) -> WA rows 0:2048, cols 0:1280
      t = 2048 * 1280;
      pack_perm<<<(t + 255) / 256, blk, 0, stream>>>(
          W_ih0 + (size_t)s * 2048 * 1280, WA, 1280, 1280, 1792, 0, t);
      // W_hh0 (gate-interleaved) -> WA rows 0:2048, cols 1280:1792
      t = 2048 * 512;
      pack_perm<<<(t + 255) / 256, blk, 0, stream>>>(
          W_hh0 + (size_t)s * 2048 * 512, WA, 512, 512, 1792, 1280, t);
      // hwN_W0 x-part -> WA rows 2048:2560, cols 0:1280, zero-pad 1280:1792
      t = 512 * 1792;
      pack_w<<<(t + 255) / 256, blk, 0, stream>>>(
          hwN_W0 + (size_t)s * 512 * 1792, WA, 1792, 512, 1280, 1792, 1792,
          (long)2048 * 1792, t);
      // hwL_W0 -> WA rows 2560:3072, cols 0:1280, zero-pad 1280:1792
      pack_w<<<(t + 255) / 256, blk, 0, stream>>>(
          hwL_W0 + (size_t)s * 512 * 1280, WA, 1792, 512, 1280, 1280, 1792,
          (long)2560 * 1792, t);
      // hwN_W0 h-part (src cols 1280:1792) -> WH [512,512]
      t = 512 * 512;
      pack_w<<<(t + 255) / 256, blk, 0, stream>>>(
          hwN_W0 + (size_t)s * 512 * 1792 + 1280, WH, 512, 512, 512, 1792, 512, 0, t);
      // W_ih1 (gate-interleaved) -> WB cols 0:512
      t = 2048 * 512;
      pack_perm<<<(t + 255) / 256, blk, 0, stream>>>(
          W_ih1 + (size_t)s * 2048 * 512, WB, 512, 512, 1024, 0, t);
      // W_hh1 (gate-interleaved) -> WB cols 512:1024
      pack_perm<<<(t + 255) / 256, blk, 0, stream>>>(
          W_hh1 + (size_t)s * 2048 * 512, WB, 512, 512, 1024, 512, t);
      // sh_W -> WS
      t = 256 * 512;
      pack_w<<<(t + 255) / 256, blk, 0, stream>>>(
          sh_W + (size_t)s * 256 * 512, WS, 512, 256, 512, 512, 512, 0, t);
      // pred_W -> WP (pad rows 100:128 with zeros)
      t = 128 * 256;
      pack_w<<<(t + 255) / 256, blk, 0, stream>>>(
          pred_W + (size_t)s * 100 * 256, WP, 256, 100, 256, 256, 256, 0, t);
    }

    // GEMM0 (MODE 4): cols 0:2048 -> fused LSTM-0 (h -> h0new, c0);
    //                 cols 2048:3072 -> ghw fp32 [hwN-x | hwL]
    gemm_bt<4><<<dim3(24, 64), blk, 0, stream>>>(
        xh, 1792, WA, 1792, nullptr, 0,
        b_ih0 + s * 2048, b_hh0 + s * 2048, c0, h0new, 512, 0,
        nullptr, ghw, nullptr, BATCH, 3072, 1792, 2048);
    // gemm_hwy (MODE 6): acc = h0new @ WH^T; fused highway -> cur (xcur[:,0:512]);
    //                    also copies h0new -> xh[:,1280:1792]
    gemm_bt<6><<<dim3(4, 64), blk, 0, stream>>>(
        h0new, 512, WH, 512, xcur, 1024,
        hwN_b0 + s * 512, nullptr, nullptr, xh, 1792, 1280,
        ghw, nullptr, h0new, BATCH, 512, 512, 512);
    // teacher-forced embedding for next slot (GEMM0 already consumed current emb)
    if (s < SLOTS - 1)
      emb_gather<<<BATCH * 256 / 256, blk, 0, stream>>>(
          emb + (size_t)s * 100 * 256, labels + (size_t)s * BATCH, xh);
    // GEMM1 (MODE 4, all-LSTM): [cur|h1] @ WB^T -> fused LSTM-1 (h -> xnext[:,512:1024], c1)
    gemm_bt<4><<<dim3(16, 64), blk, 0, stream>>>(
        xcur, 1024, WB, 1024, nullptr, 0,
        b_ih1 + s * 2048, b_hh1 + s * 2048, c1, xnext, 1024, 512,
        nullptr, nullptr, nullptr, BATCH, 2048, 1024, 2048);
    // sh (MODE 1): hidden = relu(h1 @ sh_W^T + sh_b) bf16
    gemm_bt<1><<<dim3(2, 64), blk, 0, stream>>>(
        xnext + 512, 1024, WS, 512, hidden, 256,
        sh_b + s * 256, nullptr, nullptr, nullptr, 0, 0,
        nullptr, nullptr, nullptr, BATCH, 256, 512, 256);
    // pred (MODE 2): logits -> d_out[s]
    gemm_bt<2><<<dim3(1, 64), blk, 0, stream>>>(
        hidden, 256, WP, 256, out + (size_t)s * BATCH * 100, 100,
        pred_b + s * 100, nullptr, nullptr, nullptr, 0, 0,
        nullptr, nullptr, nullptr, BATCH, 128, 256, 100);
  }
}

// Round 4
// 1889.036 us; speedup vs baseline: 1.1220x; 1.0383x over previous
//
#include <hip/hip_runtime.h>

#define SLOTS 7
#define BATCH 8192

typedef __attribute__((ext_vector_type(8))) __bf16 bf16x8;
typedef __attribute__((ext_vector_type(4))) float f32x4;

__device__ __forceinline__ void gl_lds16(const __bf16* g, __bf16* l) {
  __builtin_amdgcn_global_load_lds(
      (const __attribute__((address_space(1))) void*)g,
      (__attribute__((address_space(3))) void*)l, 16, 0, 0);
}

__device__ __forceinline__ float sigmoidf_(float x) {
  return 1.f / (1.f + __expf(-x));
}
__device__ __forceinline__ float tanhf_(float x) {
  float xc = fminf(fmaxf(x, -15.f), 15.f);
  float e = __expf(2.f * xc);
  return (e - 1.f) / (e + 1.f);
}

#define VMW(n) asm volatile("s_waitcnt vmcnt(" #n ")" ::: "memory")
#define BAR() __builtin_amdgcn_s_barrier()
#define FENCE() asm volatile("" ::: "memory")

// ---------------------------------------------------------------------------
// 8-phase 256x256 GEMM (T3+T4+T5), C = A[M,K] @ Bw[N,K]^T, fused LSTM epilogue.
// BK=64 as two K-halves [256 rows][32 k] (64B row stride -> conflict-free
// ds_read_b128 fragment reads). LDS slots per buffer: 0=A-kh0,1=B-kh0,
// 2=A-kh1,3=B-kh1; phase q stages slot q of tile t+1.
// Steady-state waits: vmcnt(6) at phases 0,2; last tile drains 4 -> 0.
// Epilogue: cols < Nreal: gate-interleaved LSTM cell (col c -> gate (c>>4)&3,
// unit h=(c>>6)*16+(c&15)); cols >= Nreal: fp32 store to auxw (ld 1024).
// ---------------------------------------------------------------------------
__global__ void __launch_bounds__(512, 2)
gemm8p(const __bf16* __restrict__ A, int lda,
       const __bf16* __restrict__ Bw, int ldb,
       const float* __restrict__ b_ih, const float* __restrict__ b_hh,
       float* __restrict__ cst, __bf16* __restrict__ hout, int hld, int hoff,
       float* __restrict__ auxw,
       int N, int NT, int Nreal) {
  extern __shared__ __bf16 lds[];  // 2 buf x 4 slots x 8192 elems = 128 KiB
#define LDSH(b, s) (lds + (((b) << 2) + (s)) * 8192)
  const int tid = threadIdx.x;
  const int w = tid >> 6, lane = tid & 63;
  const int wr = w >> 2, wc = w & 3;
  const int ln = lane & 15, lh = lane >> 4;
  const int nbx = N >> 8;
  const int NB = gridDim.x;
  const int bid = blockIdx.x;
  const int wg = (bid & 7) * (NB >> 3) + (bid >> 3);  // XCD swizzle (NB%8==0)
  const int bx = wg % nbx, by = wg / nbx;
  const int blockM = by << 8, blockN = bx << 8;

  f32x4 acc[8][4];
#pragma unroll
  for (int i = 0; i < 8; ++i)
#pragma unroll
    for (int j = 0; j < 4; ++j) acc[i][j] = (f32x4){0.f, 0.f, 0.f, 0.f};

  // stage one half-tile (slot s) of K-tile kt into buffer nb
  auto stage = [&](int nb, int s, int kt) {
    const __bf16* base = (s & 1) ? Bw : A;
    const int ld = (s & 1) ? ldb : lda;
    const int rb = (s & 1) ? blockN : blockM;
    const int kh = s >> 1;
#pragma unroll
    for (int j = 0; j < 2; ++j) {
      const int off = j * 4096 + w * 512 + lane * 8;  // elem offset in half
      const int row = off >> 5;
      const int blk = (off >> 3) & 3;
      const __bf16* src =
          base + (size_t)(rb + row) * ld + kt * 64 + kh * 32 + blk * 8;
      gl_lds16(src, LDSH(nb, s) + j * 4096 + w * 512);  // wave-uniform dest
    }
  };

  bf16x8 a[8], bb[2];
  const int aoff = lh << 3;  // k sub-offset within half (8 elems)

#define RDA(slot)                                                            \
  {                                                                          \
    const __bf16* ap = LDSH(buf, slot);                                      \
    _Pragma("unroll") for (int mi = 0; mi < 8; ++mi) a[mi] =                 \
        *(const bf16x8*)&ap[(wr * 128 + mi * 16 + ln) * 32 + aoff];          \
  }
#define RDB(slot, nh)                                                        \
  {                                                                          \
    const __bf16* bp = LDSH(buf, slot);                                      \
    _Pragma("unroll") for (int ni = 0; ni < 2; ++ni) bb[ni] =                \
        *(const bf16x8*)&bp[(wc * 64 + (nh)*32 + ni * 16 + ln) * 32 + aoff]; \
  }
#define MFMA16(nh)                                                           \
  __builtin_amdgcn_s_setprio(1);                                             \
  _Pragma("unroll") for (int mi = 0; mi < 8; ++mi)                           \
      _Pragma("unroll") for (int ni = 0; ni < 2; ++ni)                       \
          acc[mi][(nh)*2 + ni] = __builtin_amdgcn_mfma_f32_16x16x32_bf16(    \
              a[mi], bb[ni], acc[mi][(nh)*2 + ni], 0, 0, 0);                 \
  __builtin_amdgcn_s_setprio(0);

  // prologue: stage K-tile 0 into buf 0 (slots 0..3 in order)
#pragma unroll
  for (int s4 = 0; s4 < 4; ++s4) stage(0, s4, 0);

  int buf = 0;
  for (int t = 0; t < NT; ++t) {
    const int nb = buf ^ 1;
    const bool hn = (t + 1 < NT);
    // ---- phase 0: kh0, nh0 ----
    if (hn) { stage(nb, 0, t + 1); VMW(6); } else { VMW(4); }
    BAR();
    RDA(0); RDB(1, 0);
    MFMA16(0);
    FENCE(); BAR();
    // ---- phase 1: kh0, nh1 ----
    if (hn) stage(nb, 1, t + 1);
    BAR();
    RDB(1, 1);
    MFMA16(1);
    FENCE(); BAR();
    // ---- phase 2: kh1, nh0 ----
    if (hn) { stage(nb, 2, t + 1); VMW(6); } else { VMW(0); }
    BAR();
    RDA(2); RDB(3, 0);
    MFMA16(0);
    FENCE(); BAR();
    // ---- phase 3: kh1, nh1 ----
    if (hn) stage(nb, 3, t + 1);
    BAR();
    RDB(3, 1);
    MFMA16(1);
    FENCE(); BAR();
    buf = nb;
  }
#undef RDA
#undef RDB
#undef MFMA16
#undef LDSH

  // ---- epilogue ----
  const int row0 = blockM + wr * 128 + (lh << 2);
  if (blockN < Nreal) {  // LSTM region (gate-interleaved cols)
    const int h = (((blockN >> 6) + wc) << 4) + ln;
    const float bs0 = b_ih[h] + b_hh[h];
    const float bs1 = b_ih[512 + h] + b_hh[512 + h];
    const float bs2 = b_ih[1024 + h] + b_hh[1024 + h];
    const float bs3 = b_ih[1536 + h] + b_hh[1536 + h];
#pragma unroll
    for (int mi = 0; mi < 8; ++mi)
#pragma unroll
      for (int r = 0; r < 4; ++r) {
        const int row = row0 + mi * 16 + r;
        float gi = sigmoidf_(acc[mi][0][r] + bs0);
        float gf = sigmoidf_(acc[mi][1][r] + bs1);
        float gg = tanhf_(acc[mi][2][r] + bs2);
        float go = sigmoidf_(acc[mi][3][r] + bs3);
        const size_t ci = (size_t)row * 512 + h;
        float cn = gf * cst[ci] + gi * gg;
        cst[ci] = cn;
        hout[(size_t)row * hld + hoff + h] = (__bf16)(go * tanhf_(cn));
      }
  } else {  // aux fp32 region -> auxw (ld 1024), no bias
#pragma unroll
    for (int mi = 0; mi < 8; ++mi)
#pragma unroll
      for (int n = 0; n < 4; ++n) {
        const int col = blockN - Nreal + wc * 64 + n * 16 + ln;
#pragma unroll
        for (int r = 0; r < 4; ++r)
          auxw[(size_t)(row0 + mi * 16 + r) * 1024 + col] = acc[mi][n][r];
      }
  }
}

// ---------------------------------------------------------------------------
// 2-phase 128x128 GEMM for the small layers.
// MODE 1: bf16 store, bias + relu     MODE 2: fp32 store, bias, col<Nreal
// MODE 6: highway epilogue: sig(acc + aux_x + bias)*hn + (1-g)*aux_l
// ---------------------------------------------------------------------------
template <int MODE>
__global__ void __launch_bounds__(256)
gemm_bt(const __bf16* __restrict__ A, int lda,
        const __bf16* __restrict__ Bw, int ldb,
        void* __restrict__ Cout, int ldc,
        const float* __restrict__ bias,
        const float* __restrict__ auxr,
        __bf16* __restrict__ hout, int hld, int hoff,
        const __bf16* __restrict__ hsrc,
        int M, int N, int K, int Nreal) {
  __shared__ __align__(16) __bf16 As[2][128 * 32];
  __shared__ __align__(16) __bf16 Bs[2][128 * 32];
  const int w = threadIdx.x >> 6;
  const int lane = threadIdx.x & 63;
  const int wr = w >> 1, wc = w & 1;
  const int rowBase = blockIdx.y << 7;
  const int colBase = blockIdx.x << 7;
  const int sr = lane >> 2;
  const int sc = (lane & 3) << 3;

  f32x4 acc[4][4];
#pragma unroll
  for (int i = 0; i < 4; ++i)
#pragma unroll
    for (int j = 0; j < 4; ++j) acc[i][j] = (f32x4){0.f, 0.f, 0.f, 0.f};

  const int nsteps = K >> 5;

#define STAGE(bi, k0)                                                           \
  {                                                                             \
    const __bf16* ga = A + (size_t)(rowBase + (w << 5) + sr) * lda + (k0) + sc; \
    gl_lds16(ga, &As[(bi)][(w << 5) * 32]);                                     \
    gl_lds16(ga + (size_t)16 * lda, &As[(bi)][((w << 5) + 16) * 32]);           \
    const __bf16* gb = Bw + (size_t)(colBase + (w << 5) + sr) * ldb + (k0) + sc;\
    gl_lds16(gb, &Bs[(bi)][(w << 5) * 32]);                                     \
    gl_lds16(gb + (size_t)16 * ldb, &Bs[(bi)][((w << 5) + 16) * 32]);           \
  }

  STAGE(0, 0);
  __syncthreads();
  int buf = 0;
  const int ln = lane & 15;
  const int kg = (lane >> 4) << 3;
  for (int t = 0; t < nsteps; ++t) {
    if (t + 1 < nsteps) STAGE(buf ^ 1, (t + 1) << 5);
    bf16x8 av[4], bv[4];
#pragma unroll
    for (int i = 0; i < 4; ++i)
      av[i] = *(const bf16x8*)&As[buf][((wr << 6) + (i << 4) + ln) * 32 + kg];
#pragma unroll
    for (int i = 0; i < 4; ++i)
      bv[i] = *(const bf16x8*)&Bs[buf][((wc << 6) + (i << 4) + ln) * 32 + kg];
#pragma unroll
    for (int mi = 0; mi < 4; ++mi)
#pragma unroll
      for (int ni = 0; ni < 4; ++ni)
        acc[mi][ni] = __builtin_amdgcn_mfma_f32_16x16x32_bf16(
            av[mi], bv[ni], acc[mi][ni], 0, 0, 0);
    __syncthreads();
    buf ^= 1;
  }
#undef STAGE

  const int lh = lane >> 4;
  const int row0 = rowBase + (wr << 6) + (lh << 2);
  const int col0 = colBase + (wc << 6) + ln;

  if (MODE == 1) {  // bf16, bias + relu
    __bf16* C = (__bf16*)Cout;
#pragma unroll
    for (int mi = 0; mi < 4; ++mi)
#pragma unroll
      for (int ni = 0; ni < 4; ++ni) {
        const int col = col0 + (ni << 4);
        const float b = bias[col];
#pragma unroll
        for (int r = 0; r < 4; ++r) {
          float v = fmaxf(acc[mi][ni][r] + b, 0.f);
          C[(size_t)(row0 + (mi << 4) + r) * ldc + col] = (__bf16)v;
        }
      }
  } else if (MODE == 2) {  // fp32, bias, bounded cols
    float* C = (float*)Cout;
#pragma unroll
    for (int mi = 0; mi < 4; ++mi)
#pragma unroll
      for (int ni = 0; ni < 4; ++ni) {
        const int col = col0 + (ni << 4);
        if (col < Nreal) {
          const float b = bias[col];
#pragma unroll
          for (int r = 0; r < 4; ++r)
            C[(size_t)(row0 + (mi << 4) + r) * ldc + col] = acc[mi][ni][r] + b;
        }
      }
  } else if (MODE == 6) {  // highway combine
    __bf16* C = (__bf16*)Cout;
#pragma unroll
    for (int mi = 0; mi < 4; ++mi)
#pragma unroll
      for (int ni = 0; ni < 4; ++ni) {
        const int col = col0 + (ni << 4);
#pragma unroll
        for (int r = 0; r < 4; ++r) {
          const int row = row0 + (mi << 4) + r;
          float xp = auxr[(size_t)row * 1024 + col];
          float hwl = auxr[(size_t)row * 1024 + 512 + col];
          float gn = sigmoidf_(acc[mi][ni][r] + xp + bias[col]);
          float hn = (float)hsrc[(size_t)row * 512 + col];
          C[(size_t)row * ldc + col] = (__bf16)(gn * hn + (1.f - gn) * hwl);
          hout[(size_t)row * hld + hoff + col] = (__bf16)hn;  // h0 -> xh
        }
      }
  }
}

// ---------------------------------------------------------------------------
// Weight pack kernels (single slot): fp32 -> bf16.
// ---------------------------------------------------------------------------
__global__ void pack_w(const float* __restrict__ src, __bf16* __restrict__ dst,
                       int cols, int rows_s, int cols_s,
                       int sLd, int dLd, long dOff, int total) {
  int idx = blockIdx.x * 256 + threadIdx.x;
  if (idx >= total) return;
  int r = idx / cols;
  int c = idx - r * cols;
  float v = (r < rows_s && c < cols_s) ? src[(long)r * sLd + c] : 0.f;
  dst[dOff + (long)r * dLd + c] = (__bf16)v;
}

// gate-interleaved pack: dst row r <- src row ((r>>4)&3)*512 + (r>>6)*16 + (r&15)
__global__ void pack_perm(const float* __restrict__ src, __bf16* __restrict__ dst,
                          int cols, int sLd, int dLd, long dColOff, int total) {
  int idx = blockIdx.x * 256 + threadIdx.x;
  if (idx >= total) return;
  int r = idx / cols;
  int c = idx - r * cols;
  int srcr = (((r >> 4) & 3) << 9) + ((r >> 6) << 4) + (r & 15);
  dst[(long)r * dLd + dColOff + c] = (__bf16)src[(long)srcr * sLd + c];
}

__global__ void conv_inputs(const float* __restrict__ in, __bf16* __restrict__ xh) {
  int idx = blockIdx.x * 256 + threadIdx.x;  // B*1024
  int b = idx >> 10, c = idx & 1023;
  xh[(size_t)b * 1792 + c] = (__bf16)in[idx];
}

__global__ void set_start(const float* __restrict__ start, __bf16* __restrict__ xh) {
  int idx = blockIdx.x * 256 + threadIdx.x;  // B*256
  int b = idx >> 8, e = idx & 255;
  xh[(size_t)b * 1792 + 1024 + e] = (__bf16)start[e];
}

__global__ void emb_gather(const float* __restrict__ emb, const int* __restrict__ labels,
                           __bf16* __restrict__ xh) {
  int idx = blockIdx.x * 256 + threadIdx.x;  // B*256
  int b = idx >> 8, e = idx & 255;
  int lab = labels[b];
  xh[(size_t)b * 1792 + 1024 + e] = (__bf16)emb[(size_t)lab * 256 + e];
}

__global__ void zero_states(__bf16* __restrict__ xh, __bf16* __restrict__ xh1A) {
  int idx = blockIdx.x * 256 + threadIdx.x;  // B*512
  int b = idx >> 9, h = idx & 511;
  xh[(size_t)b * 1792 + 1280 + h] = (__bf16)0.f;   // h0 = 0
  xh1A[(size_t)b * 1024 + 512 + h] = (__bf16)0.f;  // h1 = 0 (buffer 0)
}

extern "C" void kernel_launch(void* const* d_in, const int* in_sizes, int n_in,
                              void* d_out, int out_size, void* d_ws, size_t ws_size,
                              hipStream_t stream) {
  const float* inputs = (const float*)d_in[0];
  const int* labels = (const int*)d_in[1];
  const float* start = (const float*)d_in[2];
  const float* emb = (const float*)d_in[3];
  const float* W_ih0 = (const float*)d_in[4];
  const float* W_hh0 = (const float*)d_in[5];
  const float* b_ih0 = (const float*)d_in[6];
  const float* b_hh0 = (const float*)d_in[7];
  const float* hwN_W0 = (const float*)d_in[8];
  const float* hwN_b0 = (const float*)d_in[9];
  const float* hwL_W0 = (const float*)d_in[10];
  const float* W_ih1 = (const float*)d_in[11];
  const float* W_hh1 = (const float*)d_in[12];
  const float* b_ih1 = (const float*)d_in[13];
  const float* b_hh1 = (const float*)d_in[14];
  // d_in[15..17]: hwN_W1 / hwN_b1 / hwL_W1 — dead in reference, skipped
  const float* sh_W = (const float*)d_in[18];
  const float* sh_b = (const float*)d_in[19];
  const float* pred_W = (const float*)d_in[20];
  const float* pred_b = (const float*)d_in[21];
  float* out = (float*)d_out;

  char* p = (char*)d_ws;
  size_t off = 0;
  auto alloc = [&](size_t bytes) {
    void* r = p + off;
    off += (bytes + 255) & ~(size_t)255;
    return r;
  };
  __bf16* WA = (__bf16*)alloc((size_t)3072 * 1792 * 2);  // [ih0|hh0 perm; hwNx|0; hwL|0]
  __bf16* WH = (__bf16*)alloc((size_t)512 * 512 * 2);    // hwN h-part
  __bf16* WB = (__bf16*)alloc((size_t)2048 * 1024 * 2);  // [ih1|hh1 perm]
  __bf16* WS = (__bf16*)alloc((size_t)256 * 512 * 2);    // sh_W
  __bf16* WP = (__bf16*)alloc((size_t)128 * 256 * 2);    // pred_W padded
  __bf16* xh = (__bf16*)alloc((size_t)BATCH * 1792 * 2);   // [inputs | emb | h0]
  __bf16* xh1A = (__bf16*)alloc((size_t)BATCH * 1024 * 2); // ping-pong [cur | h1]
  __bf16* xh1B = (__bf16*)alloc((size_t)BATCH * 1024 * 2);
  __bf16* h0new = (__bf16*)alloc((size_t)BATCH * 512 * 2);
  float* ghw = (float*)alloc((size_t)BATCH * 1024 * 4);  // [hwN-x | hwL] fp32
  float* c0 = (float*)alloc((size_t)BATCH * 512 * 4);
  float* c1 = (float*)alloc((size_t)BATCH * 512 * 4);
  __bf16* hidden = (__bf16*)ghw;  // aliases ghw (dead after hwy GEMM)
  (void)ws_size; (void)in_sizes; (void)n_in; (void)out_size;

  hipMemsetAsync(c0, 0, (size_t)BATCH * 512 * 4, stream);
  hipMemsetAsync(c1, 0, (size_t)BATCH * 512 * 4, stream);
  zero_states<<<BATCH * 512 / 256, 256, 0, stream>>>(xh, xh1A);
  conv_inputs<<<BATCH * 1024 / 256, 256, 0, stream>>>(inputs, xh);
  set_start<<<BATCH * 256 / 256, 256, 0, stream>>>(start, xh);

  const dim3 blk(256);
  for (int s = 0; s < SLOTS; ++s) {
    __bf16* xcur = (s & 1) ? xh1B : xh1A;
    __bf16* xnext = (s & 1) ? xh1A : xh1B;
    // ---- pack this slot's weights ----
    {
      int t;
      t = 2048 * 1280;
      pack_perm<<<(t + 255) / 256, blk, 0, stream>>>(
          W_ih0 + (size_t)s * 2048 * 1280, WA, 1280, 1280, 1792, 0, t);
      t = 2048 * 512;
      pack_perm<<<(t + 255) / 256, blk, 0, stream>>>(
          W_hh0 + (size_t)s * 2048 * 512, WA, 512, 512, 1792, 1280, t);
      t = 512 * 1792;
      pack_w<<<(t + 255) / 256, blk, 0, stream>>>(
          hwN_W0 + (size_t)s * 512 * 1792, WA, 1792, 512, 1280, 1792, 1792,
          (long)2048 * 1792, t);
      pack_w<<<(t + 255) / 256, blk, 0, stream>>>(
          hwL_W0 + (size_t)s * 512 * 1280, WA, 1792, 512, 1280, 1280, 1792,
          (long)2560 * 1792, t);
      t = 512 * 512;
      pack_w<<<(t + 255) / 256, blk, 0, stream>>>(
          hwN_W0 + (size_t)s * 512 * 1792 + 1280, WH, 512, 512, 512, 1792, 512, 0, t);
      t = 2048 * 512;
      pack_perm<<<(t + 255) / 256, blk, 0, stream>>>(
          W_ih1 + (size_t)s * 2048 * 512, WB, 512, 512, 1024, 0, t);
      pack_perm<<<(t + 255) / 256, blk, 0, stream>>>(
          W_hh1 + (size_t)s * 2048 * 512, WB, 512, 512, 1024, 512, t);
      t = 256 * 512;
      pack_w<<<(t + 255) / 256, blk, 0, stream>>>(
          sh_W + (size_t)s * 256 * 512, WS, 512, 256, 512, 512, 512, 0, t);
      t = 128 * 256;
      pack_w<<<(t + 255) / 256, blk, 0, stream>>>(
          pred_W + (size_t)s * 100 * 256, WP, 256, 100, 256, 256, 256, 0, t);
    }

    // GEMM0 (8-phase): cols 0:2048 fused LSTM-0 (h->h0new, c0); 2048:3072 -> ghw
    gemm8p<<<384, 512, 131072, stream>>>(
        xh, 1792, WA, 1792, b_ih0 + s * 2048, b_hh0 + s * 2048,
        c0, h0new, 512, 0, ghw, 3072, 28, 2048);
    // hwy (MODE 6): acc = h0new @ WH^T; highway -> cur; h0new copied into xh
    gemm_bt<6><<<dim3(4, 64), blk, 0, stream>>>(
        h0new, 512, WH, 512, xcur, 1024, hwN_b0 + s * 512,
        ghw, xh, 1792, 1280, h0new, BATCH, 512, 512, 512);
    // teacher-forced embedding for next slot (GEMM0 already consumed current emb)
    if (s < SLOTS - 1)
      emb_gather<<<BATCH * 256 / 256, blk, 0, stream>>>(
          emb + (size_t)s * 100 * 256, labels + (size_t)s * BATCH, xh);
    // GEMM1 (8-phase): [cur|h1] @ WB^T -> fused LSTM-1 (h -> xnext[:,512:1024], c1)
    gemm8p<<<256, 512, 131072, stream>>>(
        xcur, 1024, WB, 1024, b_ih1 + s * 2048, b_hh1 + s * 2048,
        c1, xnext, 1024, 512, nullptr, 2048, 16, 2048);
    // sh (MODE 1): hidden = relu(h1 @ sh_W^T + sh_b) bf16
    gemm_bt<1><<<dim3(2, 64), blk, 0, stream>>>(
        xnext + 512, 1024, WS, 512, hidden, 256, sh_b + s * 256,
        nullptr, nullptr, 0, 0, nullptr, BATCH, 256, 512, 256);
    // pred (MODE 2): logits -> d_out[s]
    gemm_bt<2><<<dim3(1, 64), blk, 0, stream>>>(
        hidden, 256, WP, 256, out + (size_t)s * BATCH * 100, 100,
        pred_b + s * 100, nullptr, nullptr, 0, 0, nullptr, BATCH, 128, 256, 100);
  }
}

// Round 7
// 1800.739 us; speedup vs baseline: 1.1770x; 1.0490x over previous
//
#include <hip/hip_runtime.h>

#define SLOTS 7
#define BATCH 8192

typedef __attribute__((ext_vector_type(8))) __bf16 bf16x8;
typedef __attribute__((ext_vector_type(4))) float f32x4;

__device__ __forceinline__ void gl_lds16(const __bf16* g, __bf16* l) {
  __builtin_amdgcn_global_load_lds(
      (const __attribute__((address_space(1))) void*)g,
      (__attribute__((address_space(3))) void*)l, 16, 0, 0);
}

__device__ __forceinline__ float sigmoidf_(float x) {
  return 1.f / (1.f + __expf(-x));
}
__device__ __forceinline__ float tanhf_(float x) {
  float xc = fminf(fmaxf(x, -15.f), 15.f);
  float e = __expf(2.f * xc);
  return (e - 1.f) / (e + 1.f);
}

#define VMW(n) asm volatile("s_waitcnt vmcnt(" #n ")" ::: "memory")
// s_barrier is IntrNoMem in LLVM: memory ops may be hoisted/sunk across it.
// BARF pairs it with a zero-cost compiler memory fence so ds_reads placed
// after the barrier cannot execute before it (r6 race: read hoisted between
// this wave's vmcnt drain and the barrier -> saw other waves' unlanded loads).
#define BARF()                       \
  __builtin_amdgcn_s_barrier();      \
  asm volatile("" ::: "memory")
#define LGKM0()                                        \
  asm volatile("s_waitcnt lgkmcnt(0)" ::: "memory");   \
  __builtin_amdgcn_sched_barrier(0)

// ---------------------------------------------------------------------------
// 8-phase 256x256 GEMM (T2+T3+T4+T5), C = A[M,K] @ Bw[N,K]^T, fused LSTM epi.
// BK=64 as two K-halves [256 rows][32 k]. Chunk swizzle (T2, rule #21):
// LDS stays LINEAR (global_load_lds); the per-lane GLOBAL source k-block is
// pre-permuted blk_log = blk_phys ^ ((row>>1)&3); ds_reads apply the same XOR.
// RACE RULES: (1) reads of a staged slot must be covered by a (vmcnt; barrier)
// pair at an earlier phase boundary — vmcnt is per-wave only; (2) every
// barrier needs a compiler memory fence (BARF) or reads hoist across it.
// Drains: VMW(4)+BARF prologue (covers s0,s1 of tile 0); VMW(4) [VMW(0) last
// tile] after ph1 MFMA (covers s2,s3); VMW(4) after ph3 MFMA (next s0,s1).
// Epilogue: cols<Nreal gate-interleaved LSTM (col c -> gate (c>>4)&3, unit
// h=(c>>6)*16+(c&15)); cols>=Nreal: fp32 -> auxw (ld 1024).
// ---------------------------------------------------------------------------
__global__ void __launch_bounds__(512, 2)
gemm8p(const __bf16* __restrict__ A, int lda,
       const __bf16* __restrict__ Bw, int ldb,
       const float* __restrict__ b_ih, const float* __restrict__ b_hh,
       float* __restrict__ cst, __bf16* __restrict__ hout, int hld, int hoff,
       float* __restrict__ auxw,
       int N, int NT, int Nreal) {
  extern __shared__ __bf16 lds[];  // 2 buf x 4 slots x 8192 elems = 128 KiB
#define LDSH(b, s) (lds + (((b) << 2) + (s)) * 8192)
  const int tid = threadIdx.x;
  const int w = tid >> 6, lane = tid & 63;
  const int wr = w >> 2, wc = w & 3;
  const int ln = lane & 15, lh = lane >> 4;
  const int nbx = N >> 8;
  const int NB = gridDim.x;
  const int bid = blockIdx.x;
  const int wg = (bid & 7) * (NB >> 3) + (bid >> 3);  // XCD swizzle (NB%8==0)
  const int bx = wg % nbx, by = wg / nbx;
  const int blockM = by << 8, blockN = bx << 8;

  f32x4 acc[8][4];
#pragma unroll
  for (int i = 0; i < 8; ++i)
#pragma unroll
    for (int j = 0; j < 4; ++j) acc[i][j] = (f32x4){0.f, 0.f, 0.f, 0.f};

  // stage one half-tile (slot s) of K-tile kt into buffer nb.
  // LDS dest linear; global source k-block pre-swizzled (T2 rule #21).
  auto stage = [&](int nb, int s, int kt) {
    const __bf16* base = (s & 1) ? Bw : A;
    const int ld = (s & 1) ? ldb : lda;
    const int rb = (s & 1) ? blockN : blockM;
    const int kh = s >> 1;
#pragma unroll
    for (int j = 0; j < 2; ++j) {
      const int c = j * 512 + w * 64 + lane;  // 16B chunk index in half-tile
      const int row = c >> 2;
      const int blklog = (c & 3) ^ ((c >> 3) & 3);  // (c>>3)&3 == (row>>1)&3
      const __bf16* src =
          base + (size_t)(rb + row) * ld + kt * 64 + kh * 32 + blklog * 8;
      gl_lds16(src, LDSH(nb, s) + j * 4096 + w * 512);  // wave-uniform dest
    }
  };

  bf16x8 a[8], bb[2];
  // swizzled k sub-offset: logical blk lh at row -> phys blk lh^((row>>1)&3);
  // (row>>1)&3 == (ln>>1)&3 for every fragment row here (row%16 == ln).
  const int swz = ((lh ^ ((ln >> 1) & 3)) << 3);

#define RDA(slot)                                                            \
  {                                                                          \
    const __bf16* ap = LDSH(buf, slot);                                      \
    _Pragma("unroll") for (int mi = 0; mi < 8; ++mi) a[mi] =                 \
        *(const bf16x8*)&ap[(wr * 128 + mi * 16 + ln) * 32 + swz];           \
  }
#define RDB(slot, nh)                                                        \
  {                                                                          \
    const __bf16* bp = LDSH(buf, slot);                                      \
    _Pragma("unroll") for (int ni = 0; ni < 2; ++ni) bb[ni] =                \
        *(const bf16x8*)&bp[(wc * 64 + (nh)*32 + ni * 16 + ln) * 32 + swz];  \
  }
#define MFMA16(nh)                                                           \
  __builtin_amdgcn_s_setprio(1);                                             \
  _Pragma("unroll") for (int mi = 0; mi < 8; ++mi)                           \
      _Pragma("unroll") for (int ni = 0; ni < 2; ++ni)                       \
          acc[mi][(nh)*2 + ni] = __builtin_amdgcn_mfma_f32_16x16x32_bf16(    \
              a[mi], bb[ni], acc[mi][(nh)*2 + ni], 0, 0, 0);                 \
  __builtin_amdgcn_s_setprio(0);

  // prologue: stage K-tile 0 (8 loads); drain s0,s1 and make it global
#pragma unroll
  for (int s4 = 0; s4 < 4; ++s4) stage(0, s4, 0);
  VMW(4);
  BARF();

  int buf = 0;
  for (int t = 0; t < NT; ++t) {
    const int nb = buf ^ 1;
    const bool hn = (t + 1 < NT);
    // ---- phase 0: kh0, nh0 ---- (s0,s1 drained at prev ph3 / prologue)
    RDA(0); RDB(1, 0);
    if (hn) stage(nb, 0, t + 1);
    BARF();
    LGKM0();
    MFMA16(0);
    BARF();
    // ---- phase 1: kh0, nh1 ----
    RDB(1, 1);
    if (hn) stage(nb, 1, t + 1);
    BARF();
    LGKM0();
    MFMA16(1);
    if (hn) { VMW(4); } else { VMW(0); }  // drain s2,s3 of tile t
    BARF();
    // ---- phase 2: kh1, nh0 ----
    RDA(2); RDB(3, 0);
    if (hn) stage(nb, 2, t + 1);
    BARF();
    LGKM0();
    MFMA16(0);
    BARF();
    // ---- phase 3: kh1, nh1 ----
    RDB(3, 1);
    if (hn) stage(nb, 3, t + 1);
    BARF();
    LGKM0();
    MFMA16(1);
    if (hn) { VMW(4); }  // drain s0,s1 of tile t+1 (last tile: nothing left)
    BARF();
    buf = nb;
  }
#undef RDA
#undef RDB
#undef MFMA16
#undef LDSH

  // ---- epilogue ----
  const int row0 = blockM + wr * 128 + (lh << 2);
  if (blockN < Nreal) {  // LSTM region (gate-interleaved cols)
    const int h = (((blockN >> 6) + wc) << 4) + ln;
    const float bs0 = b_ih[h] + b_hh[h];
    const float bs1 = b_ih[512 + h] + b_hh[512 + h];
    const float bs2 = b_ih[1024 + h] + b_hh[1024 + h];
    const float bs3 = b_ih[1536 + h] + b_hh[1536 + h];
#pragma unroll
    for (int mi = 0; mi < 8; ++mi)
#pragma unroll
      for (int r = 0; r < 4; ++r) {
        const int row = row0 + mi * 16 + r;
        float gi = sigmoidf_(acc[mi][0][r] + bs0);
        float gf = sigmoidf_(acc[mi][1][r] + bs1);
        float gg = tanhf_(acc[mi][2][r] + bs2);
        float go = sigmoidf_(acc[mi][3][r] + bs3);
        const size_t ci = (size_t)row * 512 + h;
        float cn = gf * cst[ci] + gi * gg;
        cst[ci] = cn;
        hout[(size_t)row * hld + hoff + h] = (__bf16)(go * tanhf_(cn));
      }
  } else {  // aux fp32 region -> auxw (ld 1024), no bias
#pragma unroll
    for (int mi = 0; mi < 8; ++mi)
#pragma unroll
      for (int n = 0; n < 4; ++n) {
        const int col = blockN - Nreal + wc * 64 + n * 16 + ln;
#pragma unroll
        for (int r = 0; r < 4; ++r)
          auxw[(size_t)(row0 + mi * 16 + r) * 1024 + col] = acc[mi][n][r];
      }
  }
}

// ---------------------------------------------------------------------------
// 2-phase 128x128 GEMM for the small layers.
// MODE 1: bf16 store, bias + relu     MODE 2: fp32 store, bias, col<Nreal
// MODE 6: highway epilogue: sig(acc + aux_x + bias)*hn + (1-g)*aux_l
// ---------------------------------------------------------------------------
template <int MODE>
__global__ void __launch_bounds__(256)
gemm_bt(const __bf16* __restrict__ A, int lda,
        const __bf16* __restrict__ Bw, int ldb,
        void* __restrict__ Cout, int ldc,
        const float* __restrict__ bias,
        const float* __restrict__ auxr,
        __bf16* __restrict__ hout, int hld, int hoff,
        const __bf16* __restrict__ hsrc,
        int M, int N, int K, int Nreal) {
  __shared__ __align__(16) __bf16 As[2][128 * 32];
  __shared__ __align__(16) __bf16 Bs[2][128 * 32];
  const int w = threadIdx.x >> 6;
  const int lane = threadIdx.x & 63;
  const int wr = w >> 1, wc = w & 1;
  const int rowBase = blockIdx.y << 7;
  const int colBase = blockIdx.x << 7;
  const int sr = lane >> 2;
  const int sc = (lane & 3) << 3;

  f32x4 acc[4][4];
#pragma unroll
  for (int i = 0; i < 4; ++i)
#pragma unroll
    for (int j = 0; j < 4; ++j) acc[i][j] = (f32x4){0.f, 0.f, 0.f, 0.f};

  const int nsteps = K >> 5;

#define STAGE(bi, k0)                                                           \
  {                                                                             \
    const __bf16* ga = A + (size_t)(rowBase + (w << 5) + sr) * lda + (k0) + sc; \
    gl_lds16(ga, &As[(bi)][(w << 5) * 32]);                                     \
    gl_lds16(ga + (size_t)16 * lda, &As[(bi)][((w << 5) + 16) * 32]);           \
    const __bf16* gb = Bw + (size_t)(colBase + (w << 5) + sr) * ldb + (k0) + sc;\
    gl_lds16(gb, &Bs[(bi)][(w << 5) * 32]);                                     \
    gl_lds16(gb + (size_t)16 * ldb, &Bs[(bi)][((w << 5) + 16) * 32]);           \
  }

  STAGE(0, 0);
  __syncthreads();
  int buf = 0;
  const int ln = lane & 15;
  const int kg = (lane >> 4) << 3;
  for (int t = 0; t < nsteps; ++t) {
    if (t + 1 < nsteps) STAGE(buf ^ 1, (t + 1) << 5);
    bf16x8 av[4], bv[4];
#pragma unroll
    for (int i = 0; i < 4; ++i)
      av[i] = *(const bf16x8*)&As[buf][((wr << 6) + (i << 4) + ln) * 32 + kg];
#pragma unroll
    for (int i = 0; i < 4; ++i)
      bv[i] = *(const bf16x8*)&Bs[buf][((wc << 6) + (i << 4) + ln) * 32 + kg];
#pragma unroll
    for (int mi = 0; mi < 4; ++mi)
#pragma unroll
      for (int ni = 0; ni < 4; ++ni)
        acc[mi][ni] = __builtin_amdgcn_mfma_f32_16x16x32_bf16(
            av[mi], bv[ni], acc[mi][ni], 0, 0, 0);
    __syncthreads();
    buf ^= 1;
  }
#undef STAGE

  const int lh = lane >> 4;
  const int row0 = rowBase + (wr << 6) + (lh << 2);
  const int col0 = colBase + (wc << 6) + ln;

  if (MODE == 1) {  // bf16, bias + relu
    __bf16* C = (__bf16*)Cout;
#pragma unroll
    for (int mi = 0; mi < 4; ++mi)
#pragma unroll
      for (int ni = 0; ni < 4; ++ni) {
        const int col = col0 + (ni << 4);
        const float b = bias[col];
#pragma unroll
        for (int r = 0; r < 4; ++r) {
          float v = fmaxf(acc[mi][ni][r] + b, 0.f);
          C[(size_t)(row0 + (mi << 4) + r) * ldc + col] = (__bf16)v;
        }
      }
  } else if (MODE == 2) {  // fp32, bias, bounded cols
    float* C = (float*)Cout;
#pragma unroll
    for (int mi = 0; mi < 4; ++mi)
#pragma unroll
      for (int ni = 0; ni < 4; ++ni) {
        const int col = col0 + (ni << 4);
        if (col < Nreal) {
          const float b = bias[col];
#pragma unroll
          for (int r = 0; r < 4; ++r)
            C[(size_t)(row0 + (mi << 4) + r) * ldc + col] = acc[mi][ni][r] + b;
        }
      }
  } else if (MODE == 6) {  // highway combine
    __bf16* C = (__bf16*)Cout;
#pragma unroll
    for (int mi = 0; mi < 4; ++mi)
#pragma unroll
      for (int ni = 0; ni < 4; ++ni) {
        const int col = col0 + (ni << 4);
#pragma unroll
        for (int r = 0; r < 4; ++r) {
          const int row = row0 + (mi << 4) + r;
          float xp = auxr[(size_t)row * 1024 + col];
          float hwl = auxr[(size_t)row * 1024 + 512 + col];
          float gn = sigmoidf_(acc[mi][ni][r] + xp + bias[col]);
          float hn = (float)hsrc[(size_t)row * 512 + col];
          C[(size_t)row * ldc + col] = (__bf16)(gn * hn + (1.f - gn) * hwl);
          hout[(size_t)row * hld + hoff + col] = (__bf16)hn;  // h0 -> xh
        }
      }
  }
}

// ---------------------------------------------------------------------------
// Weight pack kernels (single slot): fp32 -> bf16.
// ---------------------------------------------------------------------------
__global__ void pack_w(const float* __restrict__ src, __bf16* __restrict__ dst,
                       int cols, int rows_s, int cols_s,
                       int sLd, int dLd, long dOff, int total) {
  int idx = blockIdx.x * 256 + threadIdx.x;
  if (idx >= total) return;
  int r = idx / cols;
  int c = idx - r * cols;
  float v = (r < rows_s && c < cols_s) ? src[(long)r * sLd + c] : 0.f;
  dst[dOff + (long)r * dLd + c] = (__bf16)v;
}

// gate-interleaved pack: dst row r <- src row ((r>>4)&3)*512 + (r>>6)*16 + (r&15)
__global__ void pack_perm(const float* __restrict__ src, __bf16* __restrict__ dst,
                          int cols, int sLd, int dLd, long dColOff, int total) {
  int idx = blockIdx.x * 256 + threadIdx.x;
  if (idx >= total) return;
  int r = idx / cols;
  int c = idx - r * cols;
  int srcr = (((r >> 4) & 3) << 9) + ((r >> 6) << 4) + (r & 15);
  dst[(long)r * dLd + dColOff + c] = (__bf16)src[(long)srcr * sLd + c];
}

__global__ void conv_inputs(const float* __restrict__ in, __bf16* __restrict__ xh) {
  int idx = blockIdx.x * 256 + threadIdx.x;  // B*1024
  int b = idx >> 10, c = idx & 1023;
  xh[(size_t)b * 1792 + c] = (__bf16)in[idx];
}

__global__ void set_start(const float* __restrict__ start, __bf16* __restrict__ xh) {
  int idx = blockIdx.x * 256 + threadIdx.x;  // B*256
  int b = idx >> 8, e = idx & 255;
  xh[(size_t)b * 1792 + 1024 + e] = (__bf16)start[e];
}

__global__ void emb_gather(const float* __restrict__ emb, const int* __restrict__ labels,
                           __bf16* __restrict__ xh) {
  int idx = blockIdx.x * 256 + threadIdx.x;  // B*256
  int b = idx >> 8, e = idx & 255;
  int lab = labels[b];
  xh[(size_t)b * 1792 + 1024 + e] = (__bf16)emb[(size_t)lab * 256 + e];
}

__global__ void zero_states(__bf16* __restrict__ xh, __bf16* __restrict__ xh1A) {
  int idx = blockIdx.x * 256 + threadIdx.x;  // B*512
  int b = idx >> 9, h = idx & 511;
  xh[(size_t)b * 1792 + 1280 + h] = (__bf16)0.f;   // h0 = 0
  xh1A[(size_t)b * 1024 + 512 + h] = (__bf16)0.f;  // h1 = 0 (buffer 0)
}

extern "C" void kernel_launch(void* const* d_in, const int* in_sizes, int n_in,
                              void* d_out, int out_size, void* d_ws, size_t ws_size,
                              hipStream_t stream) {
  const float* inputs = (const float*)d_in[0];
  const int* labels = (const int*)d_in[1];
  const float* start = (const float*)d_in[2];
  const float* emb = (const float*)d_in[3];
  const float* W_ih0 = (const float*)d_in[4];
  const float* W_hh0 = (const float*)d_in[5];
  const float* b_ih0 = (const float*)d_in[6];
  const float* b_hh0 = (const float*)d_in[7];
  const float* hwN_W0 = (const float*)d_in[8];
  const float* hwN_b0 = (const float*)d_in[9];
  const float* hwL_W0 = (const float*)d_in[10];
  const float* W_ih1 = (const float*)d_in[11];
  const float* W_hh1 = (const float*)d_in[12];
  const float* b_ih1 = (const float*)d_in[13];
  const float* b_hh1 = (const float*)d_in[14];
  // d_in[15..17]: hwN_W1 / hwN_b1 / hwL_W1 — dead in reference, skipped
  const float* sh_W = (const float*)d_in[18];
  const float* sh_b = (const float*)d_in[19];
  const float* pred_W = (const float*)d_in[20];
  const float* pred_b = (const float*)d_in[21];
  float* out = (float*)d_out;

  char* p = (char*)d_ws;
  size_t off = 0;
  auto alloc = [&](size_t bytes) {
    void* r = p + off;
    off += (bytes + 255) & ~(size_t)255;
    return r;
  };
  __bf16* WA = (__bf16*)alloc((size_t)3072 * 1792 * 2);  // [ih0|hh0 perm; hwNx|0; hwL|0]
  __bf16* WH = (__bf16*)alloc((size_t)512 * 512 * 2);    // hwN h-part
  __bf16* WB = (__bf16*)alloc((size_t)2048 * 1024 * 2);  // [ih1|hh1 perm]
  __bf16* WS = (__bf16*)alloc((size_t)256 * 512 * 2);    // sh_W
  __bf16* WP = (__bf16*)alloc((size_t)128 * 256 * 2);    // pred_W padded
  __bf16* xh = (__bf16*)alloc((size_t)BATCH * 1792 * 2);   // [inputs | emb | h0]
  __bf16* xh1A = (__bf16*)alloc((size_t)BATCH * 1024 * 2); // ping-pong [cur | h1]
  __bf16* xh1B = (__bf16*)alloc((size_t)BATCH * 1024 * 2);
  __bf16* h0new = (__bf16*)alloc((size_t)BATCH * 512 * 2);
  float* ghw = (float*)alloc((size_t)BATCH * 1024 * 4);  // [hwN-x | hwL] fp32
  float* c0 = (float*)alloc((size_t)BATCH * 512 * 4);
  float* c1 = (float*)alloc((size_t)BATCH * 512 * 4);
  __bf16* hidden = (__bf16*)ghw;  // aliases ghw (dead after hwy GEMM)
  (void)ws_size; (void)in_sizes; (void)n_in; (void)out_size;

  hipMemsetAsync(c0, 0, (size_t)BATCH * 512 * 4, stream);
  hipMemsetAsync(c1, 0, (size_t)BATCH * 512 * 4, stream);
  zero_states<<<BATCH * 512 / 256, 256, 0, stream>>>(xh, xh1A);
  conv_inputs<<<BATCH * 1024 / 256, 256, 0, stream>>>(inputs, xh);
  set_start<<<BATCH * 256 / 256, 256, 0, stream>>>(start, xh);

  const dim3 blk(256);
  for (int s = 0; s < SLOTS; ++s) {
    __bf16* xcur = (s & 1) ? xh1B : xh1A;
    __bf16* xnext = (s & 1) ? xh1A : xh1B;
    // ---- pack this slot's weights ----
    {
      int t;
      t = 2048 * 1280;
      pack_perm<<<(t + 255) / 256, blk, 0, stream>>>(
          W_ih0 + (size_t)s * 2048 * 1280, WA, 1280, 1280, 1792, 0, t);
      t = 2048 * 512;
      pack_perm<<<(t + 255) / 256, blk, 0, stream>>>(
          W_hh0 + (size_t)s * 2048 * 512, WA, 512, 512, 1792, 1280, t);
      t = 512 * 1792;
      pack_w<<<(t + 255) / 256, blk, 0, stream>>>(
          hwN_W0 + (size_t)s * 512 * 1792, WA, 1792, 512, 1280, 1792, 1792,
          (long)2048 * 1792, t);
      pack_w<<<(t + 255) / 256, blk, 0, stream>>>(
          hwL_W0 + (size_t)s * 512 * 1280, WA, 1792, 512, 1280, 1280, 1792,
          (long)2560 * 1792, t);
      t = 512 * 512;
      pack_w<<<(t + 255) / 256, blk, 0, stream>>>(
          hwN_W0 + (size_t)s * 512 * 1792 + 1280, WH, 512, 512, 512, 1792, 512, 0, t);
      t = 2048 * 512;
      pack_perm<<<(t + 255) / 256, blk, 0, stream>>>(
          W_ih1 + (size_t)s * 2048 * 512, WB, 512, 512, 1024, 0, t);
      pack_perm<<<(t + 255) / 256, blk, 0, stream>>>(
          W_hh1 + (size_t)s * 2048 * 512, WB, 512, 512, 1024, 512, t);
      t = 256 * 512;
      pack_w<<<(t + 255) / 256, blk, 0, stream>>>(
          sh_W + (size_t)s * 256 * 512, WS, 512, 256, 512, 512, 512, 0, t);
      t = 128 * 256;
      pack_w<<<(t + 255) / 256, blk, 0, stream>>>(
          pred_W + (size_t)s * 100 * 256, WP, 256, 100, 256, 256, 256, 0, t);
    }

    // GEMM0 (8-phase): cols 0:2048 fused LSTM-0 (h->h0new, c0); 2048:3072 -> ghw
    gemm8p<<<384, 512, 131072, stream>>>(
        xh, 1792, WA, 1792, b_ih0 + s * 2048, b_hh0 + s * 2048,
        c0, h0new, 512, 0, ghw, 3072, 28, 2048);
    // hwy (MODE 6): acc = h0new @ WH^T; highway -> cur; h0new copied into xh
    gemm_bt<6><<<dim3(4, 64), blk, 0, stream>>>(
        h0new, 512, WH, 512, xcur, 1024, hwN_b0 + s * 512,
        ghw, xh, 1792, 1280, h0new, BATCH, 512, 512, 512);
    // teacher-forced embedding for next slot (GEMM0 already consumed current emb)
    if (s < SLOTS - 1)
      emb_gather<<<BATCH * 256 / 256, blk, 0, stream>>>(
          emb + (size_t)s * 100 * 256, labels + (size_t)s * BATCH, xh);
    // GEMM1 (8-phase): [cur|h1] @ WB^T -> fused LSTM-1 (h -> xnext[:,512:1024], c1)
    gemm8p<<<256, 512, 131072, stream>>>(
        xcur, 1024, WB, 1024, b_ih1 + s * 2048, b_hh1 + s * 2048,
        c1, xnext, 1024, 512, nullptr, 2048, 16, 2048);
    // sh (MODE 1): hidden = relu(h1 @ sh_W^T + sh_b) bf16
    gemm_bt<1><<<dim3(2, 64), blk, 0, stream>>>(
        xnext + 512, 1024, WS, 512, hidden, 256, sh_b + s * 256,
        nullptr, nullptr, 0, 0, nullptr, BATCH, 256, 512, 256);
    // pred (MODE 2): logits -> d_out[s]
    gemm_bt<2><<<dim3(1, 64), blk, 0, stream>>>(
        hidden, 256, WP, 256, out + (size_t)s * BATCH * 100, 100,
        pred_b + s * 100, nullptr, nullptr, 0, 0, nullptr, BATCH, 128, 256, 100);
  }
}

// Round 8
// 1729.881 us; speedup vs baseline: 1.2252x; 1.0410x over previous
//
#include <hip/hip_runtime.h>

#define SLOTS 7
#define BATCH 8192

typedef __attribute__((ext_vector_type(8))) __bf16 bf16x8;
typedef __attribute__((ext_vector_type(4))) float f32x4;

__device__ __forceinline__ void gl_lds16(const __bf16* g, __bf16* l) {
  __builtin_amdgcn_global_load_lds(
      (const __attribute__((address_space(1))) void*)g,
      (__attribute__((address_space(3))) void*)l, 16, 0, 0);
}

__device__ __forceinline__ float sigmoidf_(float x) {
  return 1.f / (1.f + __expf(-x));
}
__device__ __forceinline__ float tanhf_(float x) {
  float xc = fminf(fmaxf(x, -15.f), 15.f);
  float e = __expf(2.f * xc);
  return (e - 1.f) / (e + 1.f);
}

#define VMW(n) asm volatile("s_waitcnt vmcnt(" #n ")" ::: "memory")
// s_barrier is IntrNoMem in LLVM: pair with a compiler memory fence so LDS
// reads/writes cannot be hoisted/sunk across it (r6 race lesson).
#define BARF()                       \
  __builtin_amdgcn_s_barrier();      \
  asm volatile("" ::: "memory")

// ---------------------------------------------------------------------------
// 256x256 GEMM, 2-sync-points-per-K-tile schedule (T4 counted vmcnt, dbuf),
// C = A[M,K] @ Bw[N,K]^T, fused gate-interleaved LSTM epilogue.
// BK=64 as two K-halves [256 rows][32 k]. Chunk swizzle (T2, rule #21):
// LDS linear (global_load_lds); per-lane GLOBAL source k-block pre-permuted
// blk_log = blk_phys ^ ((row>>1)&3); ds_reads apply the same XOR. 0 bank
// conflicts (r7-verified).
// Sync design (r7 lesson: 8 barriers/K-tile lockstep-serialized reads vs
// MFMA): only 2 real hazards per K-tile -> 2 barriers:
//   mid (end of kh0): VMW(4) drains s2,s3(t) [VMW(0) last tile]; barrier
//     makes it global -> kh1 reads safe. (vmcnt is per-wave; each wave
//     stages 1/8 of every slot, so own-drain + barrier = slot complete.)
//   end (end of kh1): VMW(4) drains s0,s1(t+1); barrier also fences WAR
//     (next tile stages into the buffer last read this tile).
// No lgkmcnt(0)/sched_barrier: LDS reads are compiler-visible loads feeding
// MFMA by data dependence -> compiler emits fine-grained lgkmcnt and can
// interleave reads/stages/MFMA freely within each half-tile region.
// Per-wave load ledger (2 loads/stage): steady outstanding 4..8; drains
// always land exactly on the slots about to be read (prologue VMW(4)+BARF
// covers s0,s1 of tile 0; last tile mid-drain VMW(0)).
// Variable K-depth: blocks with blockN >= Nreal use NTaux (aux cols are
// zero-padded beyond K=NTaux*64, exact); uniform per block.
// Epilogue: cols<Nreal gate-interleaved LSTM (col c -> gate (c>>4)&3, unit
// h=(c>>6)*16+(c&15)); cols>=Nreal: fp32 -> auxw (ld 1024).
// ---------------------------------------------------------------------------
__global__ void __launch_bounds__(512, 2)
gemm8p(const __bf16* __restrict__ A, int lda,
       const __bf16* __restrict__ Bw, int ldb,
       const float* __restrict__ b_ih, const float* __restrict__ b_hh,
       float* __restrict__ cst, __bf16* __restrict__ hout, int hld, int hoff,
       float* __restrict__ auxw,
       int N, int NT, int NTaux, int Nreal) {
  extern __shared__ __bf16 lds[];  // 2 buf x 4 slots x 8192 elems = 128 KiB
#define LDSH(b, s) (lds + (((b) << 2) + (s)) * 8192)
  const int tid = threadIdx.x;
  const int w = tid >> 6, lane = tid & 63;
  const int wr = w >> 2, wc = w & 3;
  const int ln = lane & 15, lh = lane >> 4;
  const int nbx = N >> 8;
  const int NB = gridDim.x;
  const int bid = blockIdx.x;
  const int wg = (bid & 7) * (NB >> 3) + (bid >> 3);  // XCD swizzle (NB%8==0)
  const int bx = wg % nbx, by = wg / nbx;
  const int blockM = by << 8, blockN = bx << 8;
  const int nt = (blockN < Nreal) ? NT : NTaux;

  f32x4 acc[8][4];
#pragma unroll
  for (int i = 0; i < 8; ++i)
#pragma unroll
    for (int j = 0; j < 4; ++j) acc[i][j] = (f32x4){0.f, 0.f, 0.f, 0.f};

  // stage one half-tile (slot s) of K-tile kt into buffer nb.
  // LDS dest linear; global source k-block pre-swizzled (T2 rule #21).
  auto stage = [&](int nb, int s, int kt) {
    const __bf16* base = (s & 1) ? Bw : A;
    const int ld = (s & 1) ? ldb : lda;
    const int rb = (s & 1) ? blockN : blockM;
    const int kh = s >> 1;
#pragma unroll
    for (int j = 0; j < 2; ++j) {
      const int c = j * 512 + w * 64 + lane;  // 16B chunk index in half-tile
      const int row = c >> 2;
      const int blklog = (c & 3) ^ ((c >> 3) & 3);  // (c>>3)&3 == (row>>1)&3
      const __bf16* src =
          base + (size_t)(rb + row) * ld + kt * 64 + kh * 32 + blklog * 8;
      gl_lds16(src, LDSH(nb, s) + j * 4096 + w * 512);  // wave-uniform dest
    }
  };

  bf16x8 a[8], bb[2];
  // swizzled k sub-offset: logical blk lh at row -> phys blk lh^((row>>1)&3);
  // (row>>1)&3 == (ln>>1)&3 for every fragment row here (row%16 == ln).
  const int swz = ((lh ^ ((ln >> 1) & 3)) << 3);

#define RDA(slot)                                                            \
  {                                                                          \
    const __bf16* ap = LDSH(buf, slot);                                      \
    _Pragma("unroll") for (int mi = 0; mi < 8; ++mi) a[mi] =                 \
        *(const bf16x8*)&ap[(wr * 128 + mi * 16 + ln) * 32 + swz];           \
  }
#define RDB(slot, nh)                                                        \
  {                                                                          \
    const __bf16* bp = LDSH(buf, slot);                                      \
    _Pragma("unroll") for (int ni = 0; ni < 2; ++ni) bb[ni] =                \
        *(const bf16x8*)&bp[(wc * 64 + (nh)*32 + ni * 16 + ln) * 32 + swz];  \
  }
#define MFMA16(nh)                                                           \
  __builtin_amdgcn_s_setprio(1);                                             \
  _Pragma("unroll") for (int mi = 0; mi < 8; ++mi)                           \
      _Pragma("unroll") for (int ni = 0; ni < 2; ++ni)                       \
          acc[mi][(nh)*2 + ni] = __builtin_amdgcn_mfma_f32_16x16x32_bf16(    \
              a[mi], bb[ni], acc[mi][(nh)*2 + ni], 0, 0, 0);                 \
  __builtin_amdgcn_s_setprio(0);

  // prologue: stage K-tile 0 (8 loads); drain s0,s1 and make it global
#pragma unroll
  for (int s4 = 0; s4 < 4; ++s4) stage(0, s4, 0);
  VMW(4);
  BARF();

  int buf = 0;
  for (int t = 0; t < nt; ++t) {
    const int nb = buf ^ 1;
    const bool hn = (t + 1 < nt);
    // ---- K-half 0: reads s0,s1 (covered by previous boundary drain) ----
    RDA(0); RDB(1, 0);
    if (hn) stage(nb, 0, t + 1);
    MFMA16(0);
    RDB(1, 1);
    if (hn) stage(nb, 1, t + 1);
    MFMA16(1);
    if (hn) { VMW(4); } else { VMW(0); }  // drain s2,s3 of tile t
    BARF();
    // ---- K-half 1: reads s2,s3 ----
    RDA(2); RDB(3, 0);
    if (hn) stage(nb, 2, t + 1);
    MFMA16(0);
    RDB(3, 1);
    if (hn) stage(nb, 3, t + 1);
    MFMA16(1);
    if (hn) { VMW(4); }  // drain s0,s1 of tile t+1; also WAR fence below
    BARF();
    buf = nb;
  }
#undef RDA
#undef RDB
#undef MFMA16
#undef LDSH

  // ---- epilogue ----
  const int row0 = blockM + wr * 128 + (lh << 2);
  if (blockN < Nreal) {  // LSTM region (gate-interleaved cols)
    const int h = (((blockN >> 6) + wc) << 4) + ln;
    const float bs0 = b_ih[h] + b_hh[h];
    const float bs1 = b_ih[512 + h] + b_hh[512 + h];
    const float bs2 = b_ih[1024 + h] + b_hh[1024 + h];
    const float bs3 = b_ih[1536 + h] + b_hh[1536 + h];
#pragma unroll
    for (int mi = 0; mi < 8; ++mi)
#pragma unroll
      for (int r = 0; r < 4; ++r) {
        const int row = row0 + mi * 16 + r;
        float gi = sigmoidf_(acc[mi][0][r] + bs0);
        float gf = sigmoidf_(acc[mi][1][r] + bs1);
        float gg = tanhf_(acc[mi][2][r] + bs2);
        float go = sigmoidf_(acc[mi][3][r] + bs3);
        const size_t ci = (size_t)row * 512 + h;
        float cn = gf * cst[ci] + gi * gg;
        cst[ci] = cn;
        hout[(size_t)row * hld + hoff + h] = (__bf16)(go * tanhf_(cn));
      }
  } else {  // aux fp32 region -> auxw (ld 1024), no bias
#pragma unroll
    for (int mi = 0; mi < 8; ++mi)
#pragma unroll
      for (int n = 0; n < 4; ++n) {
        const int col = blockN - Nreal + wc * 64 + n * 16 + ln;
#pragma unroll
        for (int r = 0; r < 4; ++r)
          auxw[(size_t)(row0 + mi * 16 + r) * 1024 + col] = acc[mi][n][r];
      }
  }
}

// ---------------------------------------------------------------------------
// 2-phase 128x128 GEMM for the small layers.
// MODE 1: bf16 store, bias + relu     MODE 2: fp32 store, bias, col<Nreal
// MODE 6: highway epilogue: sig(acc + aux_x + bias)*hn + (1-g)*aux_l
// ---------------------------------------------------------------------------
template <int MODE>
__global__ void __launch_bounds__(256)
gemm_bt(const __bf16* __restrict__ A, int lda,
        const __bf16* __restrict__ Bw, int ldb,
        void* __restrict__ Cout, int ldc,
        const float* __restrict__ bias,
        const float* __restrict__ auxr,
        __bf16* __restrict__ hout, int hld, int hoff,
        const __bf16* __restrict__ hsrc,
        int M, int N, int K, int Nreal) {
  __shared__ __align__(16) __bf16 As[2][128 * 32];
  __shared__ __align__(16) __bf16 Bs[2][128 * 32];
  const int w = threadIdx.x >> 6;
  const int lane = threadIdx.x & 63;
  const int wr = w >> 1, wc = w & 1;
  const int rowBase = blockIdx.y << 7;
  const int colBase = blockIdx.x << 7;
  const int sr = lane >> 2;
  const int sc = (lane & 3) << 3;

  f32x4 acc[4][4];
#pragma unroll
  for (int i = 0; i < 4; ++i)
#pragma unroll
    for (int j = 0; j < 4; ++j) acc[i][j] = (f32x4){0.f, 0.f, 0.f, 0.f};

  const int nsteps = K >> 5;

#define STAGE(bi, k0)                                                           \
  {                                                                             \
    const __bf16* ga = A + (size_t)(rowBase + (w << 5) + sr) * lda + (k0) + sc; \
    gl_lds16(ga, &As[(bi)][(w << 5) * 32]);                                     \
    gl_lds16(ga + (size_t)16 * lda, &As[(bi)][((w << 5) + 16) * 32]);           \
    const __bf16* gb = Bw + (size_t)(colBase + (w << 5) + sr) * ldb + (k0) + sc;\
    gl_lds16(gb, &Bs[(bi)][(w << 5) * 32]);                                     \
    gl_lds16(gb + (size_t)16 * ldb, &Bs[(bi)][((w << 5) + 16) * 32]);           \
  }

  STAGE(0, 0);
  __syncthreads();
  int buf = 0;
  const int ln = lane & 15;
  const int kg = (lane >> 4) << 3;
  for (int t = 0; t < nsteps; ++t) {
    if (t + 1 < nsteps) STAGE(buf ^ 1, (t + 1) << 5);
    bf16x8 av[4], bv[4];
#pragma unroll
    for (int i = 0; i < 4; ++i)
      av[i] = *(const bf16x8*)&As[buf][((wr << 6) + (i << 4) + ln) * 32 + kg];
#pragma unroll
    for (int i = 0; i < 4; ++i)
      bv[i] = *(const bf16x8*)&Bs[buf][((wc << 6) + (i << 4) + ln) * 32 + kg];
#pragma unroll
    for (int mi = 0; mi < 4; ++mi)
#pragma unroll
      for (int ni = 0; ni < 4; ++ni)
        acc[mi][ni] = __builtin_amdgcn_mfma_f32_16x16x32_bf16(
            av[mi], bv[ni], acc[mi][ni], 0, 0, 0);
    __syncthreads();
    buf ^= 1;
  }
#undef STAGE

  const int lh = lane >> 4;
  const int row0 = rowBase + (wr << 6) + (lh << 2);
  const int col0 = colBase + (wc << 6) + ln;

  if (MODE == 1) {  // bf16, bias + relu
    __bf16* C = (__bf16*)Cout;
#pragma unroll
    for (int mi = 0; mi < 4; ++mi)
#pragma unroll
      for (int ni = 0; ni < 4; ++ni) {
        const int col = col0 + (ni << 4);
        const float b = bias[col];
#pragma unroll
        for (int r = 0; r < 4; ++r) {
          float v = fmaxf(acc[mi][ni][r] + b, 0.f);
          C[(size_t)(row0 + (mi << 4) + r) * ldc + col] = (__bf16)v;
        }
      }
  } else if (MODE == 2) {  // fp32, bias, bounded cols
    float* C = (float*)Cout;
#pragma unroll
    for (int mi = 0; mi < 4; ++mi)
#pragma unroll
      for (int ni = 0; ni < 4; ++ni) {
        const int col = col0 + (ni << 4);
        if (col < Nreal) {
          const float b = bias[col];
#pragma unroll
          for (int r = 0; r < 4; ++r)
            C[(size_t)(row0 + (mi << 4) + r) * ldc + col] = acc[mi][ni][r] + b;
        }
      }
  } else if (MODE == 6) {  // highway combine
    __bf16* C = (__bf16*)Cout;
#pragma unroll
    for (int mi = 0; mi < 4; ++mi)
#pragma unroll
      for (int ni = 0; ni < 4; ++ni) {
        const int col = col0 + (ni << 4);
#pragma unroll
        for (int r = 0; r < 4; ++r) {
          const int row = row0 + (mi << 4) + r;
          float xp = auxr[(size_t)row * 1024 + col];
          float hwl = auxr[(size_t)row * 1024 + 512 + col];
          float gn = sigmoidf_(acc[mi][ni][r] + xp + bias[col]);
          float hn = (float)hsrc[(size_t)row * 512 + col];
          C[(size_t)row * ldc + col] = (__bf16)(gn * hn + (1.f - gn) * hwl);
          hout[(size_t)row * hld + hoff + col] = (__bf16)hn;  // h0 -> xh
        }
      }
  }
}

// ---------------------------------------------------------------------------
// Weight pack kernels (single slot): fp32 -> bf16.
// ---------------------------------------------------------------------------
__global__ void pack_w(const float* __restrict__ src, __bf16* __restrict__ dst,
                       int cols, int rows_s, int cols_s,
                       int sLd, int dLd, long dOff, int total) {
  int idx = blockIdx.x * 256 + threadIdx.x;
  if (idx >= total) return;
  int r = idx / cols;
  int c = idx - r * cols;
  float v = (r < rows_s && c < cols_s) ? src[(long)r * sLd + c] : 0.f;
  dst[dOff + (long)r * dLd + c] = (__bf16)v;
}

// gate-interleaved pack: dst row r <- src row ((r>>4)&3)*512 + (r>>6)*16 + (r&15)
__global__ void pack_perm(const float* __restrict__ src, __bf16* __restrict__ dst,
                          int cols, int sLd, int dLd, long dColOff, int total) {
  int idx = blockIdx.x * 256 + threadIdx.x;
  if (idx >= total) return;
  int r = idx / cols;
  int c = idx - r * cols;
  int srcr = (((r >> 4) & 3) << 9) + ((r >> 6) << 4) + (r & 15);
  dst[(long)r * dLd + dColOff + c] = (__bf16)src[(long)srcr * sLd + c];
}

__global__ void conv_inputs(const float* __restrict__ in, __bf16* __restrict__ xh) {
  int idx = blockIdx.x * 256 + threadIdx.x;  // B*1024
  int b = idx >> 10, c = idx & 1023;
  xh[(size_t)b * 1792 + c] = (__bf16)in[idx];
}

__global__ void set_start(const float* __restrict__ start, __bf16* __restrict__ xh) {
  int idx = blockIdx.x * 256 + threadIdx.x;  // B*256
  int b = idx >> 8, e = idx & 255;
  xh[(size_t)b * 1792 + 1024 + e] = (__bf16)start[e];
}

__global__ void emb_gather(const float* __restrict__ emb, const int* __restrict__ labels,
                           __bf16* __restrict__ xh) {
  int idx = blockIdx.x * 256 + threadIdx.x;  // B*256
  int b = idx >> 8, e = idx & 255;
  int lab = labels[b];
  xh[(size_t)b * 1792 + 1024 + e] = (__bf16)emb[(size_t)lab * 256 + e];
}

__global__ void zero_states(__bf16* __restrict__ xh, __bf16* __restrict__ xh1A) {
  int idx = blockIdx.x * 256 + threadIdx.x;  // B*512
  int b = idx >> 9, h = idx & 511;
  xh[(size_t)b * 1792 + 1280 + h] = (__bf16)0.f;   // h0 = 0
  xh1A[(size_t)b * 1024 + 512 + h] = (__bf16)0.f;  // h1 = 0 (buffer 0)
}

extern "C" void kernel_launch(void* const* d_in, const int* in_sizes, int n_in,
                              void* d_out, int out_size, void* d_ws, size_t ws_size,
                              hipStream_t stream) {
  const float* inputs = (const float*)d_in[0];
  const int* labels = (const int*)d_in[1];
  const float* start = (const float*)d_in[2];
  const float* emb = (const float*)d_in[3];
  const float* W_ih0 = (const float*)d_in[4];
  const float* W_hh0 = (const float*)d_in[5];
  const float* b_ih0 = (const float*)d_in[6];
  const float* b_hh0 = (const float*)d_in[7];
  const float* hwN_W0 = (const float*)d_in[8];
  const float* hwN_b0 = (const float*)d_in[9];
  const float* hwL_W0 = (const float*)d_in[10];
  const float* W_ih1 = (const float*)d_in[11];
  const float* W_hh1 = (const float*)d_in[12];
  const float* b_ih1 = (const float*)d_in[13];
  const float* b_hh1 = (const float*)d_in[14];
  // d_in[15..17]: hwN_W1 / hwN_b1 / hwL_W1 — dead in reference, skipped
  const float* sh_W = (const float*)d_in[18];
  const float* sh_b = (const float*)d_in[19];
  const float* pred_W = (const float*)d_in[20];
  const float* pred_b = (const float*)d_in[21];
  float* out = (float*)d_out;

  char* p = (char*)d_ws;
  size_t off = 0;
  auto alloc = [&](size_t bytes) {
    void* r = p + off;
    off += (bytes + 255) & ~(size_t)255;
    return r;
  };
  __bf16* WA = (__bf16*)alloc((size_t)3072 * 1792 * 2);  // [ih0|hh0 perm; hwNx|0; hwL|0]
  __bf16* WH = (__bf16*)alloc((size_t)512 * 512 * 2);    // hwN h-part
  __bf16* WB = (__bf16*)alloc((size_t)2048 * 1024 * 2);  // [ih1|hh1 perm]
  __bf16* WS = (__bf16*)alloc((size_t)256 * 512 * 2);    // sh_W
  __bf16* WP = (__bf16*)alloc((size_t)128 * 256 * 2);    // pred_W padded
  __bf16* xh = (__bf16*)alloc((size_t)BATCH * 1792 * 2);   // [inputs | emb | h0]
  __bf16* xh1A = (__bf16*)alloc((size_t)BATCH * 1024 * 2); // ping-pong [cur | h1]
  __bf16* xh1B = (__bf16*)alloc((size_t)BATCH * 1024 * 2);
  __bf16* h0new = (__bf16*)alloc((size_t)BATCH * 512 * 2);
  float* ghw = (float*)alloc((size_t)BATCH * 1024 * 4);  // [hwN-x | hwL] fp32
  float* c0 = (float*)alloc((size_t)BATCH * 512 * 4);
  float* c1 = (float*)alloc((size_t)BATCH * 512 * 4);
  __bf16* hidden = (__bf16*)ghw;  // aliases ghw (dead after hwy GEMM)
  (void)ws_size; (void)in_sizes; (void)n_in; (void)out_size;

  hipMemsetAsync(c0, 0, (size_t)BATCH * 512 * 4, stream);
  hipMemsetAsync(c1, 0, (size_t)BATCH * 512 * 4, stream);
  zero_states<<<BATCH * 512 / 256, 256, 0, stream>>>(xh, xh1A);
  conv_inputs<<<BATCH * 1024 / 256, 256, 0, stream>>>(inputs, xh);
  set_start<<<BATCH * 256 / 256, 256, 0, stream>>>(start, xh);

  const dim3 blk(256);
  for (int s = 0; s < SLOTS; ++s) {
    __bf16* xcur = (s & 1) ? xh1B : xh1A;
    __bf16* xnext = (s & 1) ? xh1A : xh1B;
    // ---- pack this slot's weights ----
    {
      int t;
      t = 2048 * 1280;
      pack_perm<<<(t + 255) / 256, blk, 0, stream>>>(
          W_ih0 + (size_t)s * 2048 * 1280, WA, 1280, 1280, 1792, 0, t);
      t = 2048 * 512;
      pack_perm<<<(t + 255) / 256, blk, 0, stream>>>(
          W_hh0 + (size_t)s * 2048 * 512, WA, 512, 512, 1792, 1280, t);
      t = 512 * 1792;
      pack_w<<<(t + 255) / 256, blk, 0, stream>>>(
          hwN_W0 + (size_t)s * 512 * 1792, WA, 1792, 512, 1280, 1792, 1792,
          (long)2048 * 1792, t);
      pack_w<<<(t + 255) / 256, blk, 0, stream>>>(
          hwL_W0 + (size_t)s * 512 * 1280, WA, 1792, 512, 1280, 1280, 1792,
          (long)2560 * 1792, t);
      t = 512 * 512;
      pack_w<<<(t + 255) / 256, blk, 0, stream>>>(
          hwN_W0 + (size_t)s * 512 * 1792 + 1280, WH, 512, 512, 512, 1792, 512, 0, t);
      t = 2048 * 512;
      pack_perm<<<(t + 255) / 256, blk, 0, stream>>>(
          W_ih1 + (size_t)s * 2048 * 512, WB, 512, 512, 1024, 0, t);
      pack_perm<<<(t + 255) / 256, blk, 0, stream>>>(
          W_hh1 + (size_t)s * 2048 * 512, WB, 512, 512, 1024, 512, t);
      t = 256 * 512;
      pack_w<<<(t + 255) / 256, blk, 0, stream>>>(
          sh_W + (size_t)s * 256 * 512, WS, 512, 256, 512, 512, 512, 0, t);
      t = 128 * 256;
      pack_w<<<(t + 255) / 256, blk, 0, stream>>>(
          pred_W + (size_t)s * 100 * 256, WP, 256, 100, 256, 256, 256, 0, t);
    }

    // GEMM0: cols 0:2048 fused LSTM-0 (h->h0new, c0); 2048:3072 -> ghw.
    // Aux blocks (blockN>=2048) run NTaux=20 K-tiles (cols zero beyond K=1280).
    gemm8p<<<384, 512, 131072, stream>>>(
        xh, 1792, WA, 1792, b_ih0 + s * 2048, b_hh0 + s * 2048,
        c0, h0new, 512, 0, ghw, 3072, 28, 20, 2048);
    // hwy (MODE 6): acc = h0new @ WH^T; highway -> cur; h0new copied into xh
    gemm_bt<6><<<dim3(4, 64), blk, 0, stream>>>(
        h0new, 512, WH, 512, xcur, 1024, hwN_b0 + s * 512,
        ghw, xh, 1792, 1280, h0new, BATCH, 512, 512, 512);
    // teacher-forced embedding for next slot (GEMM0 already consumed current emb)
    if (s < SLOTS - 1)
      emb_gather<<<BATCH * 256 / 256, blk, 0, stream>>>(
          emb + (size_t)s * 100 * 256, labels + (size_t)s * BATCH, xh);
    // GEMM1: [cur|h1] @ WB^T -> fused LSTM-1 (h -> xnext[:,512:1024], c1)
    gemm8p<<<256, 512, 131072, stream>>>(
        xcur, 1024, WB, 1024, b_ih1 + s * 2048, b_hh1 + s * 2048,
        c1, xnext, 1024, 512, nullptr, 2048, 16, 16, 2048);
    // sh (MODE 1): hidden = relu(h1 @ sh_W^T + sh_b) bf16
    gemm_bt<1><<<dim3(2, 64), blk, 0, stream>>>(
        xnext + 512, 1024, WS, 512, hidden, 256, sh_b + s * 256,
        nullptr, nullptr, 0, 0, nullptr, BATCH, 256, 512, 256);
    // pred (MODE 2): logits -> d_out[s]
    gemm_bt<2><<<dim3(1, 64), blk, 0, stream>>>(
        hidden, 256, WP, 256, out + (size_t)s * BATCH * 100, 100,
        pred_b + s * 100, nullptr, nullptr, 0, 0, nullptr, BATCH, 128, 256, 100);
  }
}

// Round 9
// 1654.928 us; speedup vs baseline: 1.2807x; 1.0453x over previous
//
#include <hip/hip_runtime.h>

#define SLOTS 7
#define BATCH 8192

typedef __attribute__((ext_vector_type(8))) __bf16 bf16x8;
typedef __attribute__((ext_vector_type(4))) float f32x4;

__device__ __forceinline__ void gl_lds16(const __bf16* g, __bf16* l) {
  __builtin_amdgcn_global_load_lds(
      (const __attribute__((address_space(1))) void*)g,
      (__attribute__((address_space(3))) void*)l, 16, 0, 0);
}

__device__ __forceinline__ float sigmoidf_(float x) {
  return 1.f / (1.f + __expf(-x));
}
__device__ __forceinline__ float tanhf_(float x) {
  float xc = fminf(fmaxf(x, -15.f), 15.f);
  float e = __expf(2.f * xc);
  return (e - 1.f) / (e + 1.f);
}

#define VMW(n) asm volatile("s_waitcnt vmcnt(" #n ")" ::: "memory")
// s_barrier is IntrNoMem in LLVM: pair with a compiler memory fence so LDS
// reads/writes cannot be hoisted/sunk across it (r6 race lesson).
#define BARF()                       \
  __builtin_amdgcn_s_barrier();      \
  asm volatile("" ::: "memory")

// ---------------------------------------------------------------------------
// 256x256 GEMM, ONE sync point per K-tile, C = A[M,K] @ Bw[N,K]^T, fused
// gate-interleaved LSTM epilogue. All blocks run the LSTM epilogue (aux
// columns are computed by a separate 2-phase kernel now).
// BK=64 as two K-halves [256 rows][32 k]. Chunk swizzle (T2, rule #21):
// LDS linear (global_load_lds); per-lane GLOBAL source k-block pre-permuted
// blk_log = blk_phys ^ ((row>>1)&3); ds_reads apply the same XOR. 0 bank
// conflicts (r7/r8-verified).
// Sync design (r8 lesson: per-half drains still convoy; amortize to 1/tile):
//   - full-tile double buffer; stages for tile t+1 issued inside region t;
//   - single VMW(0)+BARF at tile end: drains ALL of t+1's stages (distance =
//     most of a tile region >> L3/HBM latency) and makes them global for
//     t+1's reads; also the WAR fence (t+1 stages overwrite buf read at t-1,
//     whose reads were register-consumed before this barrier).
//   - kh1's slots of tile t were staged in region t-1 and drained at the end
//     of t-1 -> NO mid-tile barrier needed.
// Compiler sees one 24-ds_read / 8-load / 64-MFMA region per tile and
// software-pipelines it with fine-grained lgkmcnt (m97 evidence).
// Epilogue: gate-interleaved LSTM: col c -> gate (c>>4)&3 of unit
// h=(c>>6)*16+(c&15).
// ---------------------------------------------------------------------------
__global__ void __launch_bounds__(512, 2)
gemm8p(const __bf16* __restrict__ A, int lda,
       const __bf16* __restrict__ Bw, int ldb,
       const float* __restrict__ b_ih, const float* __restrict__ b_hh,
       float* __restrict__ cst, __bf16* __restrict__ hout, int hld, int hoff,
       int N, int NT) {
  extern __shared__ __bf16 lds[];  // 2 buf x 4 slots x 8192 elems = 128 KiB
#define LDSH(b, s) (lds + (((b) << 2) + (s)) * 8192)
  const int tid = threadIdx.x;
  const int w = tid >> 6, lane = tid & 63;
  const int wr = w >> 2, wc = w & 3;
  const int ln = lane & 15, lh = lane >> 4;
  const int nbx = N >> 8;
  const int NB = gridDim.x;
  const int bid = blockIdx.x;
  const int wg = (bid & 7) * (NB >> 3) + (bid >> 3);  // XCD swizzle (NB%8==0)
  const int bx = wg % nbx, by = wg / nbx;
  const int blockM = by << 8, blockN = bx << 8;

  f32x4 acc[8][4];
#pragma unroll
  for (int i = 0; i < 8; ++i)
#pragma unroll
    for (int j = 0; j < 4; ++j) acc[i][j] = (f32x4){0.f, 0.f, 0.f, 0.f};

  // stage one half-tile (slot s) of K-tile kt into buffer nb.
  // LDS dest linear; global source k-block pre-swizzled (T2 rule #21).
  auto stage = [&](int nb, int s, int kt) {
    const __bf16* base = (s & 1) ? Bw : A;
    const int ld = (s & 1) ? ldb : lda;
    const int rb = (s & 1) ? blockN : blockM;
    const int kh = s >> 1;
#pragma unroll
    for (int j = 0; j < 2; ++j) {
      const int c = j * 512 + w * 64 + lane;  // 16B chunk index in half-tile
      const int row = c >> 2;
      const int blklog = (c & 3) ^ ((c >> 3) & 3);  // (c>>3)&3 == (row>>1)&3
      const __bf16* src =
          base + (size_t)(rb + row) * ld + kt * 64 + kh * 32 + blklog * 8;
      gl_lds16(src, LDSH(nb, s) + j * 4096 + w * 512);  // wave-uniform dest
    }
  };

  bf16x8 a[8], b0[2], b1[2];
  // swizzled k sub-offset: logical blk lh at row -> phys blk lh^((row>>1)&3);
  // (row>>1)&3 == (ln>>1)&3 for every fragment row here (row%16 == ln).
  const int swz = ((lh ^ ((ln >> 1) & 3)) << 3);

#define RDA(slot)                                                            \
  {                                                                          \
    const __bf16* ap = LDSH(buf, slot);                                      \
    _Pragma("unroll") for (int mi = 0; mi < 8; ++mi) a[mi] =                 \
        *(const bf16x8*)&ap[(wr * 128 + mi * 16 + ln) * 32 + swz];           \
  }
#define RDB(slot)                                                            \
  {                                                                          \
    const __bf16* bp = LDSH(buf, slot);                                      \
    _Pragma("unroll") for (int ni = 0; ni < 2; ++ni) {                       \
      b0[ni] = *(const bf16x8*)&bp[(wc * 64 + ni * 16 + ln) * 32 + swz];     \
      b1[ni] = *(const bf16x8*)&bp[(wc * 64 + 32 + ni * 16 + ln) * 32 + swz];\
    }                                                                        \
  }
#define MFMAC(bp, nh)                                                        \
  __builtin_amdgcn_s_setprio(1);                                             \
  _Pragma("unroll") for (int mi = 0; mi < 8; ++mi)                           \
      _Pragma("unroll") for (int ni = 0; ni < 2; ++ni)                       \
          acc[mi][(nh)*2 + ni] = __builtin_amdgcn_mfma_f32_16x16x32_bf16(    \
              a[mi], bp[ni], acc[mi][(nh)*2 + ni], 0, 0, 0);                 \
  __builtin_amdgcn_s_setprio(0);

  // prologue: stage all 4 slots of K-tile 0; drain fully; make global
#pragma unroll
  for (int s4 = 0; s4 < 4; ++s4) stage(0, s4, 0);
  VMW(0);
  BARF();

  int buf = 0;
  for (int t = 0; t < NT; ++t) {
    const int nb = buf ^ 1;
    const bool hn = (t + 1 < NT);
    // ---- K-half 0 (slots 0,1 of tile t; staged in region t-1) ----
    RDA(0); RDB(1);
    if (hn) { stage(nb, 0, t + 1); stage(nb, 1, t + 1); }
    MFMAC(b0, 0); MFMAC(b1, 1);
    // ---- K-half 1 (slots 2,3 of tile t; also staged in region t-1) ----
    RDA(2); RDB(3);
    if (hn) { stage(nb, 2, t + 1); stage(nb, 3, t + 1); }
    MFMAC(b0, 0); MFMAC(b1, 1);
    // single sync point: drain t+1's 8 stages (issued this region), fence
    VMW(0);
    BARF();
    buf = nb;
  }
#undef RDA
#undef RDB
#undef MFMAC
#undef LDSH

  // ---- epilogue: gate-interleaved LSTM cell ----
  const int row0 = blockM + wr * 128 + (lh << 2);
  const int h = (((blockN >> 6) + wc) << 4) + ln;
  const float bs0 = b_ih[h] + b_hh[h];
  const float bs1 = b_ih[512 + h] + b_hh[512 + h];
  const float bs2 = b_ih[1024 + h] + b_hh[1024 + h];
  const float bs3 = b_ih[1536 + h] + b_hh[1536 + h];
#pragma unroll
  for (int mi = 0; mi < 8; ++mi)
#pragma unroll
    for (int r = 0; r < 4; ++r) {
      const int row = row0 + mi * 16 + r;
      float gi = sigmoidf_(acc[mi][0][r] + bs0);
      float gf = sigmoidf_(acc[mi][1][r] + bs1);
      float gg = tanhf_(acc[mi][2][r] + bs2);
      float go = sigmoidf_(acc[mi][3][r] + bs3);
      const size_t ci = (size_t)row * 512 + h;
      float cn = gf * cst[ci] + gi * gg;
      cst[ci] = cn;
      hout[(size_t)row * hld + hoff + h] = (__bf16)(go * tanhf_(cn));
    }
}

// ---------------------------------------------------------------------------
// 2-phase 128x128 GEMM for the small layers.
// MODE 0: fp32 plain store            MODE 1: bf16 store, bias + relu
// MODE 2: fp32 store, bias, col<Nreal
// MODE 6: highway epilogue: sig(acc + aux_x + bias)*hn + (1-g)*aux_l
// ---------------------------------------------------------------------------
template <int MODE>
__global__ void __launch_bounds__(256)
gemm_bt(const __bf16* __restrict__ A, int lda,
        const __bf16* __restrict__ Bw, int ldb,
        void* __restrict__ Cout, int ldc,
        const float* __restrict__ bias,
        const float* __restrict__ auxr,
        __bf16* __restrict__ hout, int hld, int hoff,
        const __bf16* __restrict__ hsrc,
        int M, int N, int K, int Nreal) {
  __shared__ __align__(16) __bf16 As[2][128 * 32];
  __shared__ __align__(16) __bf16 Bs[2][128 * 32];
  const int w = threadIdx.x >> 6;
  const int lane = threadIdx.x & 63;
  const int wr = w >> 1, wc = w & 1;
  const int rowBase = blockIdx.y << 7;
  const int colBase = blockIdx.x << 7;
  const int sr = lane >> 2;
  const int sc = (lane & 3) << 3;

  f32x4 acc[4][4];
#pragma unroll
  for (int i = 0; i < 4; ++i)
#pragma unroll
    for (int j = 0; j < 4; ++j) acc[i][j] = (f32x4){0.f, 0.f, 0.f, 0.f};

  const int nsteps = K >> 5;

#define STAGE(bi, k0)                                                           \
  {                                                                             \
    const __bf16* ga = A + (size_t)(rowBase + (w << 5) + sr) * lda + (k0) + sc; \
    gl_lds16(ga, &As[(bi)][(w << 5) * 32]);                                     \
    gl_lds16(ga + (size_t)16 * lda, &As[(bi)][((w << 5) + 16) * 32]);           \
    const __bf16* gb = Bw + (size_t)(colBase + (w << 5) + sr) * ldb + (k0) + sc;\
    gl_lds16(gb, &Bs[(bi)][(w << 5) * 32]);                                     \
    gl_lds16(gb + (size_t)16 * ldb, &Bs[(bi)][((w << 5) + 16) * 32]);           \
  }

  STAGE(0, 0);
  __syncthreads();
  int buf = 0;
  const int ln = lane & 15;
  const int kg = (lane >> 4) << 3;
  for (int t = 0; t < nsteps; ++t) {
    if (t + 1 < nsteps) STAGE(buf ^ 1, (t + 1) << 5);
    bf16x8 av[4], bv[4];
#pragma unroll
    for (int i = 0; i < 4; ++i)
      av[i] = *(const bf16x8*)&As[buf][((wr << 6) + (i << 4) + ln) * 32 + kg];
#pragma unroll
    for (int i = 0; i < 4; ++i)
      bv[i] = *(const bf16x8*)&Bs[buf][((wc << 6) + (i << 4) + ln) * 32 + kg];
#pragma unroll
    for (int mi = 0; mi < 4; ++mi)
#pragma unroll
      for (int ni = 0; ni < 4; ++ni)
        acc[mi][ni] = __builtin_amdgcn_mfma_f32_16x16x32_bf16(
            av[mi], bv[ni], acc[mi][ni], 0, 0, 0);
    __syncthreads();
    buf ^= 1;
  }
#undef STAGE

  const int lh = lane >> 4;
  const int row0 = rowBase + (wr << 6) + (lh << 2);
  const int col0 = colBase + (wc << 6) + ln;

  if (MODE == 0) {  // fp32 plain
    float* C = (float*)Cout;
#pragma unroll
    for (int mi = 0; mi < 4; ++mi)
#pragma unroll
      for (int ni = 0; ni < 4; ++ni) {
        const int col = col0 + (ni << 4);
#pragma unroll
        for (int r = 0; r < 4; ++r)
          C[(size_t)(row0 + (mi << 4) + r) * ldc + col] = acc[mi][ni][r];
      }
  } else if (MODE == 1) {  // bf16, bias + relu
    __bf16* C = (__bf16*)Cout;
#pragma unroll
    for (int mi = 0; mi < 4; ++mi)
#pragma unroll
      for (int ni = 0; ni < 4; ++ni) {
        const int col = col0 + (ni << 4);
        const float b = bias[col];
#pragma unroll
        for (int r = 0; r < 4; ++r) {
          float v = fmaxf(acc[mi][ni][r] + b, 0.f);
          C[(size_t)(row0 + (mi << 4) + r) * ldc + col] = (__bf16)v;
        }
      }
  } else if (MODE == 2) {  // fp32, bias, bounded cols
    float* C = (float*)Cout;
#pragma unroll
    for (int mi = 0; mi < 4; ++mi)
#pragma unroll
      for (int ni = 0; ni < 4; ++ni) {
        const int col = col0 + (ni << 4);
        if (col < Nreal) {
          const float b = bias[col];
#pragma unroll
          for (int r = 0; r < 4; ++r)
            C[(size_t)(row0 + (mi << 4) + r) * ldc + col] = acc[mi][ni][r] + b;
        }
      }
  } else if (MODE == 6) {  // highway combine
    __bf16* C = (__bf16*)Cout;
#pragma unroll
    for (int mi = 0; mi < 4; ++mi)
#pragma unroll
      for (int ni = 0; ni < 4; ++ni) {
        const int col = col0 + (ni << 4);
#pragma unroll
        for (int r = 0; r < 4; ++r) {
          const int row = row0 + (mi << 4) + r;
          float xp = auxr[(size_t)row * 1024 + col];
          float hwl = auxr[(size_t)row * 1024 + 512 + col];
          float gn = sigmoidf_(acc[mi][ni][r] + xp + bias[col]);
          float hn = (float)hsrc[(size_t)row * 512 + col];
          C[(size_t)row * ldc + col] = (__bf16)(gn * hn + (1.f - gn) * hwl);
          hout[(size_t)row * hld + hoff + col] = (__bf16)hn;  // h0 -> xh
        }
      }
  }
}

// ---------------------------------------------------------------------------
// Weight pack kernels (single slot): fp32 -> bf16.
// ---------------------------------------------------------------------------
__global__ void pack_w(const float* __restrict__ src, __bf16* __restrict__ dst,
                       int cols, int rows_s, int cols_s,
                       int sLd, int dLd, long dOff, int total) {
  int idx = blockIdx.x * 256 + threadIdx.x;
  if (idx >= total) return;
  int r = idx / cols;
  int c = idx - r * cols;
  float v = (r < rows_s && c < cols_s) ? src[(long)r * sLd + c] : 0.f;
  dst[dOff + (long)r * dLd + c] = (__bf16)v;
}

// gate-interleaved pack: dst row r <- src row ((r>>4)&3)*512 + (r>>6)*16 + (r&15)
__global__ void pack_perm(const float* __restrict__ src, __bf16* __restrict__ dst,
                          int cols, int sLd, int dLd, long dColOff, int total) {
  int idx = blockIdx.x * 256 + threadIdx.x;
  if (idx >= total) return;
  int r = idx / cols;
  int c = idx - r * cols;
  int srcr = (((r >> 4) & 3) << 9) + ((r >> 6) << 4) + (r & 15);
  dst[(long)r * dLd + dColOff + c] = (__bf16)src[(long)srcr * sLd + c];
}

__global__ void conv_inputs(const float* __restrict__ in, __bf16* __restrict__ xh) {
  int idx = blockIdx.x * 256 + threadIdx.x;  // B*1024
  int b = idx >> 10, c = idx & 1023;
  xh[(size_t)b * 1792 + c] = (__bf16)in[idx];
}

__global__ void set_start(const float* __restrict__ start, __bf16* __restrict__ xh) {
  int idx = blockIdx.x * 256 + threadIdx.x;  // B*256
  int b = idx >> 8, e = idx & 255;
  xh[(size_t)b * 1792 + 1024 + e] = (__bf16)start[e];
}

__global__ void emb_gather(const float* __restrict__ emb, const int* __restrict__ labels,
                           __bf16* __restrict__ xh) {
  int idx = blockIdx.x * 256 + threadIdx.x;  // B*256
  int b = idx >> 8, e = idx & 255;
  int lab = labels[b];
  xh[(size_t)b * 1792 + 1024 + e] = (__bf16)emb[(size_t)lab * 256 + e];
}

__global__ void zero_states(__bf16* __restrict__ xh, __bf16* __restrict__ xh1A) {
  int idx = blockIdx.x * 256 + threadIdx.x;  // B*512
  int b = idx >> 9, h = idx & 511;
  xh[(size_t)b * 1792 + 1280 + h] = (__bf16)0.f;   // h0 = 0
  xh1A[(size_t)b * 1024 + 512 + h] = (__bf16)0.f;  // h1 = 0 (buffer 0)
}

extern "C" void kernel_launch(void* const* d_in, const int* in_sizes, int n_in,
                              void* d_out, int out_size, void* d_ws, size_t ws_size,
                              hipStream_t stream) {
  const float* inputs = (const float*)d_in[0];
  const int* labels = (const int*)d_in[1];
  const float* start = (const float*)d_in[2];
  const float* emb = (const float*)d_in[3];
  const float* W_ih0 = (const float*)d_in[4];
  const float* W_hh0 = (const float*)d_in[5];
  const float* b_ih0 = (const float*)d_in[6];
  const float* b_hh0 = (const float*)d_in[7];
  const float* hwN_W0 = (const float*)d_in[8];
  const float* hwN_b0 = (const float*)d_in[9];
  const float* hwL_W0 = (const float*)d_in[10];
  const float* W_ih1 = (const float*)d_in[11];
  const float* W_hh1 = (const float*)d_in[12];
  const float* b_ih1 = (const float*)d_in[13];
  const float* b_hh1 = (const float*)d_in[14];
  // d_in[15..17]: hwN_W1 / hwN_b1 / hwL_W1 — dead in reference, skipped
  const float* sh_W = (const float*)d_in[18];
  const float* sh_b = (const float*)d_in[19];
  const float* pred_W = (const float*)d_in[20];
  const float* pred_b = (const float*)d_in[21];
  float* out = (float*)d_out;

  char* p = (char*)d_ws;
  size_t off = 0;
  auto alloc = [&](size_t bytes) {
    void* r = p + off;
    off += (bytes + 255) & ~(size_t)255;
    return r;
  };
  __bf16* WA = (__bf16*)alloc((size_t)2048 * 1792 * 2);  // [ih0|hh0 gate-perm]
  __bf16* WX = (__bf16*)alloc((size_t)1024 * 1280 * 2);  // [hwN-x ; hwL] K=1280
  __bf16* WH = (__bf16*)alloc((size_t)512 * 512 * 2);    // hwN h-part
  __bf16* WB = (__bf16*)alloc((size_t)2048 * 1024 * 2);  // [ih1|hh1 gate-perm]
  __bf16* WS = (__bf16*)alloc((size_t)256 * 512 * 2);    // sh_W
  __bf16* WP = (__bf16*)alloc((size_t)128 * 256 * 2);    // pred_W padded
  __bf16* xh = (__bf16*)alloc((size_t)BATCH * 1792 * 2);   // [inputs | emb | h0]
  __bf16* xh1A = (__bf16*)alloc((size_t)BATCH * 1024 * 2); // ping-pong [cur | h1]
  __bf16* xh1B = (__bf16*)alloc((size_t)BATCH * 1024 * 2);
  __bf16* h0new = (__bf16*)alloc((size_t)BATCH * 512 * 2);
  float* ghw = (float*)alloc((size_t)BATCH * 1024 * 4);  // [hwN-x | hwL] fp32
  float* c0 = (float*)alloc((size_t)BATCH * 512 * 4);
  float* c1 = (float*)alloc((size_t)BATCH * 512 * 4);
  __bf16* hidden = (__bf16*)ghw;  // aliases ghw (dead after hwy GEMM)
  (void)ws_size; (void)in_sizes; (void)n_in; (void)out_size;

  hipMemsetAsync(c0, 0, (size_t)BATCH * 512 * 4, stream);
  hipMemsetAsync(c1, 0, (size_t)BATCH * 512 * 4, stream);
  zero_states<<<BATCH * 512 / 256, 256, 0, stream>>>(xh, xh1A);
  conv_inputs<<<BATCH * 1024 / 256, 256, 0, stream>>>(inputs, xh);
  set_start<<<BATCH * 256 / 256, 256, 0, stream>>>(start, xh);

  const dim3 blk(256);
  for (int s = 0; s < SLOTS; ++s) {
    __bf16* xcur = (s & 1) ? xh1B : xh1A;
    __bf16* xnext = (s & 1) ? xh1A : xh1B;
    // ---- pack this slot's weights ----
    {
      int t;
      t = 2048 * 1280;  // W_ih0 gate-perm -> WA cols 0:1280
      pack_perm<<<(t + 255) / 256, blk, 0, stream>>>(
          W_ih0 + (size_t)s * 2048 * 1280, WA, 1280, 1280, 1792, 0, t);
      t = 2048 * 512;   // W_hh0 gate-perm -> WA cols 1280:1792
      pack_perm<<<(t + 255) / 256, blk, 0, stream>>>(
          W_hh0 + (size_t)s * 2048 * 512, WA, 512, 512, 1792, 1280, t);
      t = 512 * 1280;   // hwN_W0 x-part -> WX rows 0:512
      pack_w<<<(t + 255) / 256, blk, 0, stream>>>(
          hwN_W0 + (size_t)s * 512 * 1792, WX, 1280, 512, 1280, 1792, 1280, 0, t);
      // hwL_W0 -> WX rows 512:1024
      pack_w<<<(t + 255) / 256, blk, 0, stream>>>(
          hwL_W0 + (size_t)s * 512 * 1280, WX, 1280, 512, 1280, 1280, 1280,
          (long)512 * 1280, t);
      t = 512 * 512;    // hwN_W0 h-part -> WH
      pack_w<<<(t + 255) / 256, blk, 0, stream>>>(
          hwN_W0 + (size_t)s * 512 * 1792 + 1280, WH, 512, 512, 512, 1792, 512, 0, t);
      t = 2048 * 512;   // W_ih1 / W_hh1 gate-perm -> WB
      pack_perm<<<(t + 255) / 256, blk, 0, stream>>>(
          W_ih1 + (size_t)s * 2048 * 512, WB, 512, 512, 1024, 0, t);
      pack_perm<<<(t + 255) / 256, blk, 0, stream>>>(
          W_hh1 + (size_t)s * 2048 * 512, WB, 512, 512, 1024, 512, t);
      t = 256 * 512;    // sh_W -> WS
      pack_w<<<(t + 255) / 256, blk, 0, stream>>>(
          sh_W + (size_t)s * 256 * 512, WS, 512, 256, 512, 512, 512, 0, t);
      t = 128 * 256;    // pred_W -> WP (pad rows 100:128)
      pack_w<<<(t + 255) / 256, blk, 0, stream>>>(
          pred_W + (size_t)s * 100 * 256, WP, 256, 100, 256, 256, 256, 0, t);
    }

    // aux GEMM (2-phase, high occupancy): ghw = x[:,0:1280] @ WX^T (fp32)
    gemm_bt<0><<<dim3(8, 64), blk, 0, stream>>>(
        xh, 1792, WX, 1280, ghw, 1024, nullptr,
        nullptr, nullptr, 0, 0, nullptr, BATCH, 1024, 1280, 1024);
    // GEMM0 (1-barrier/tile, 256 blocks = exactly 1 round): fused LSTM-0
    gemm8p<<<256, 512, 131072, stream>>>(
        xh, 1792, WA, 1792, b_ih0 + s * 2048, b_hh0 + s * 2048,
        c0, h0new, 512, 0, 2048, 28);
    // hwy (MODE 6): acc = h0new @ WH^T; highway -> cur; h0new copied into xh
    gemm_bt<6><<<dim3(4, 64), blk, 0, stream>>>(
        h0new, 512, WH, 512, xcur, 1024, hwN_b0 + s * 512,
        ghw, xh, 1792, 1280, h0new, BATCH, 512, 512, 512);
    // teacher-forced embedding for next slot (aux+GEMM0 consumed current emb)
    if (s < SLOTS - 1)
      emb_gather<<<BATCH * 256 / 256, blk, 0, stream>>>(
          emb + (size_t)s * 100 * 256, labels + (size_t)s * BATCH, xh);
    // GEMM1 (256 blocks, 1 round): [cur|h1] @ WB^T -> fused LSTM-1
    gemm8p<<<256, 512, 131072, stream>>>(
        xcur, 1024, WB, 1024, b_ih1 + s * 2048, b_hh1 + s * 2048,
        c1, xnext, 1024, 512, 2048, 16);
    // sh (MODE 1): hidden = relu(h1 @ sh_W^T + sh_b) bf16
    gemm_bt<1><<<dim3(2, 64), blk, 0, stream>>>(
        xnext + 512, 1024, WS, 512, hidden, 256, sh_b + s * 256,
        nullptr, nullptr, 0, 0, nullptr, BATCH, 256, 512, 256);
    // pred (MODE 2): logits -> d_out[s]
    gemm_bt<2><<<dim3(1, 64), blk, 0, stream>>>(
        hidden, 256, WP, 256, out + (size_t)s * BATCH * 100, 100,
        pred_b + s * 100, nullptr, nullptr, 0, 0, nullptr, BATCH, 128, 256, 100);
  }
}

// Round 10
// 1539.689 us; speedup vs baseline: 1.3766x; 1.0748x over previous
//
#include <hip/hip_runtime.h>

#define SLOTS 7
#define BATCH 8192

typedef __attribute__((ext_vector_type(8))) __bf16 bf16x8;
typedef __attribute__((ext_vector_type(4))) float f32x4;

__device__ __forceinline__ void gl_lds16(const __bf16* g, __bf16* l) {
  __builtin_amdgcn_global_load_lds(
      (const __attribute__((address_space(1))) void*)g,
      (__attribute__((address_space(3))) void*)l, 16, 0, 0);
}

__device__ __forceinline__ float sigmoidf_(float x) {
  return 1.f / (1.f + __expf(-x));
}
__device__ __forceinline__ float tanhf_(float x) {
  float xc = fminf(fmaxf(x, -15.f), 15.f);
  float e = __expf(2.f * xc);
  return (e - 1.f) / (e + 1.f);
}

#define VMW(n) asm volatile("s_waitcnt vmcnt(" #n ")" ::: "memory")
// s_barrier is IntrNoMem in LLVM: pair with a compiler memory fence so LDS
// reads/writes cannot be hoisted/sunk across it (r6 race lesson).
#define BARF()                       \
  __builtin_amdgcn_s_barrier();      \
  asm volatile("" ::: "memory")

// ---------------------------------------------------------------------------
// 256x256 GEMM, ONE sync point per K-tile, C = A[M,K] @ Bw[N,K]^T, fused
// gate-interleaved LSTM epilogue.
// BK=64 as two K-halves [256 rows][32 k]. Chunk swizzle (T2, rule #21):
// LDS linear (global_load_lds); per-lane GLOBAL source k-block pre-permuted
// blk_log = blk_phys ^ ((row>>1)&3); ds_reads apply the same XOR. 0 bank
// conflicts (r7-r9 verified).
// r9 lesson: stages issued mid-region leave < HBM-latency of cover before the
// end-of-tile vmcnt(0) drain -> ALL stages for t+1 now issue at region START
// (legal: buffer nb's last readers finished before the end-of-(t-1) barrier),
// giving a full region (~2500+ cyc) of MFMA/ds_read cover.
// Epilogue: gate-interleaved LSTM: col c -> gate (c>>4)&3 of unit
// h=(c>>6)*16+(c&15).
// ---------------------------------------------------------------------------
__global__ void __launch_bounds__(512, 2)
gemm8p(const __bf16* __restrict__ A, int lda,
       const __bf16* __restrict__ Bw, int ldb,
       const float* __restrict__ b_ih, const float* __restrict__ b_hh,
       float* __restrict__ cst, __bf16* __restrict__ hout, int hld, int hoff,
       int N, int NT) {
  extern __shared__ __bf16 lds[];  // 2 buf x 4 slots x 8192 elems = 128 KiB
#define LDSH(b, s) (lds + (((b) << 2) + (s)) * 8192)
  const int tid = threadIdx.x;
  const int w = tid >> 6, lane = tid & 63;
  const int wr = w >> 2, wc = w & 3;
  const int ln = lane & 15, lh = lane >> 4;
  const int nbx = N >> 8;
  const int NB = gridDim.x;
  const int bid = blockIdx.x;
  const int wg = (bid & 7) * (NB >> 3) + (bid >> 3);  // XCD swizzle (NB%8==0)
  const int bx = wg % nbx, by = wg / nbx;
  const int blockM = by << 8, blockN = bx << 8;

  f32x4 acc[8][4];
#pragma unroll
  for (int i = 0; i < 8; ++i)
#pragma unroll
    for (int j = 0; j < 4; ++j) acc[i][j] = (f32x4){0.f, 0.f, 0.f, 0.f};

  // stage one half-tile (slot s) of K-tile kt into buffer nb.
  // LDS dest linear; global source k-block pre-swizzled (T2 rule #21).
  auto stage = [&](int nb, int s, int kt) {
    const __bf16* base = (s & 1) ? Bw : A;
    const int ld = (s & 1) ? ldb : lda;
    const int rb = (s & 1) ? blockN : blockM;
    const int kh = s >> 1;
#pragma unroll
    for (int j = 0; j < 2; ++j) {
      const int c = j * 512 + w * 64 + lane;  // 16B chunk index in half-tile
      const int row = c >> 2;
      const int blklog = (c & 3) ^ ((c >> 3) & 3);  // (c>>3)&3 == (row>>1)&3
      const __bf16* src =
          base + (size_t)(rb + row) * ld + kt * 64 + kh * 32 + blklog * 8;
      gl_lds16(src, LDSH(nb, s) + j * 4096 + w * 512);  // wave-uniform dest
    }
  };

  bf16x8 a[8], b0[2], b1[2];
  // swizzled k sub-offset: logical blk lh at row -> phys blk lh^((row>>1)&3);
  // (row>>1)&3 == (ln>>1)&3 for every fragment row here (row%16 == ln).
  const int swz = ((lh ^ ((ln >> 1) & 3)) << 3);

#define RDA(slot)                                                            \
  {                                                                          \
    const __bf16* ap = LDSH(buf, slot);                                      \
    _Pragma("unroll") for (int mi = 0; mi < 8; ++mi) a[mi] =                 \
        *(const bf16x8*)&ap[(wr * 128 + mi * 16 + ln) * 32 + swz];           \
  }
#define RDB(slot)                                                            \
  {                                                                          \
    const __bf16* bp = LDSH(buf, slot);                                      \
    _Pragma("unroll") for (int ni = 0; ni < 2; ++ni) {                       \
      b0[ni] = *(const bf16x8*)&bp[(wc * 64 + ni * 16 + ln) * 32 + swz];     \
      b1[ni] = *(const bf16x8*)&bp[(wc * 64 + 32 + ni * 16 + ln) * 32 + swz];\
    }                                                                        \
  }
#define MFMAC(bp, nh)                                                        \
  __builtin_amdgcn_s_setprio(1);                                             \
  _Pragma("unroll") for (int mi = 0; mi < 8; ++mi)                           \
      _Pragma("unroll") for (int ni = 0; ni < 2; ++ni)                       \
          acc[mi][(nh)*2 + ni] = __builtin_amdgcn_mfma_f32_16x16x32_bf16(    \
              a[mi], bp[ni], acc[mi][(nh)*2 + ni], 0, 0, 0);                 \
  __builtin_amdgcn_s_setprio(0);

  // prologue: stage all 4 slots of K-tile 0; drain fully; make global
#pragma unroll
  for (int s4 = 0; s4 < 4; ++s4) stage(0, s4, 0);
  VMW(0);
  BARF();

  int buf = 0;
  for (int t = 0; t < NT; ++t) {
    const int nb = buf ^ 1;
    const bool hn = (t + 1 < NT);
    // issue ALL of tile t+1's stages first: max drain distance (r9 lesson)
    if (hn) {
      stage(nb, 0, t + 1); stage(nb, 1, t + 1);
      stage(nb, 2, t + 1); stage(nb, 3, t + 1);
    }
    // ---- K-half 0 (slots 0,1 of tile t; staged in region t-1) ----
    RDA(0); RDB(1);
    MFMAC(b0, 0); MFMAC(b1, 1);
    // ---- K-half 1 (slots 2,3 of tile t) ----
    RDA(2); RDB(3);
    MFMAC(b0, 0); MFMAC(b1, 1);
    // single sync point: drain t+1's 8 stages (issued a full region ago)
    VMW(0);
    BARF();
    buf = nb;
  }
#undef RDA
#undef RDB
#undef MFMAC
#undef LDSH

  // ---- epilogue: gate-interleaved LSTM cell ----
  const int row0 = blockM + wr * 128 + (lh << 2);
  const int h = (((blockN >> 6) + wc) << 4) + ln;
  const float bs0 = b_ih[h] + b_hh[h];
  const float bs1 = b_ih[512 + h] + b_hh[512 + h];
  const float bs2 = b_ih[1024 + h] + b_hh[1024 + h];
  const float bs3 = b_ih[1536 + h] + b_hh[1536 + h];
#pragma unroll
  for (int mi = 0; mi < 8; ++mi)
#pragma unroll
    for (int r = 0; r < 4; ++r) {
      const int row = row0 + mi * 16 + r;
      float gi = sigmoidf_(acc[mi][0][r] + bs0);
      float gf = sigmoidf_(acc[mi][1][r] + bs1);
      float gg = tanhf_(acc[mi][2][r] + bs2);
      float go = sigmoidf_(acc[mi][3][r] + bs3);
      const size_t ci = (size_t)row * 512 + h;
      float cn = gf * cst[ci] + gi * gg;
      cst[ci] = cn;
      hout[(size_t)row * hld + hoff + h] = (__bf16)(go * tanhf_(cn));
    }
}

// ---------------------------------------------------------------------------
// 2-phase 128x128 GEMM for the small layers.
// MODE 0: fp32 plain store            MODE 1: bf16 store, bias + relu
// MODE 2: fp32 store, bias, col<Nreal
// MODE 6: highway epilogue: sig(acc + aux_x + bias)*hn + (1-g)*aux_l
// ---------------------------------------------------------------------------
template <int MODE>
__global__ void __launch_bounds__(256)
gemm_bt(const __bf16* __restrict__ A, int lda,
        const __bf16* __restrict__ Bw, int ldb,
        void* __restrict__ Cout, int ldc,
        const float* __restrict__ bias,
        const float* __restrict__ auxr,
        __bf16* __restrict__ hout, int hld, int hoff,
        const __bf16* __restrict__ hsrc,
        int M, int N, int K, int Nreal) {
  __shared__ __align__(16) __bf16 As[2][128 * 32];
  __shared__ __align__(16) __bf16 Bs[2][128 * 32];
  const int w = threadIdx.x >> 6;
  const int lane = threadIdx.x & 63;
  const int wr = w >> 1, wc = w & 1;
  const int rowBase = blockIdx.y << 7;
  const int colBase = blockIdx.x << 7;
  const int sr = lane >> 2;
  const int sc = (lane & 3) << 3;

  f32x4 acc[4][4];
#pragma unroll
  for (int i = 0; i < 4; ++i)
#pragma unroll
    for (int j = 0; j < 4; ++j) acc[i][j] = (f32x4){0.f, 0.f, 0.f, 0.f};

  const int nsteps = K >> 5;

#define STAGE(bi, k0)                                                           \
  {                                                                             \
    const __bf16* ga = A + (size_t)(rowBase + (w << 5) + sr) * lda + (k0) + sc; \
    gl_lds16(ga, &As[(bi)][(w << 5) * 32]);                                     \
    gl_lds16(ga + (size_t)16 * lda, &As[(bi)][((w << 5) + 16) * 32]);           \
    const __bf16* gb = Bw + (size_t)(colBase + (w << 5) + sr) * ldb + (k0) + sc;\
    gl_lds16(gb, &Bs[(bi)][(w << 5) * 32]);                                     \
    gl_lds16(gb + (size_t)16 * ldb, &Bs[(bi)][((w << 5) + 16) * 32]);           \
  }

  STAGE(0, 0);
  __syncthreads();
  int buf = 0;
  const int ln = lane & 15;
  const int kg = (lane >> 4) << 3;
  for (int t = 0; t < nsteps; ++t) {
    if (t + 1 < nsteps) STAGE(buf ^ 1, (t + 1) << 5);
    bf16x8 av[4], bv[4];
#pragma unroll
    for (int i = 0; i < 4; ++i)
      av[i] = *(const bf16x8*)&As[buf][((wr << 6) + (i << 4) + ln) * 32 + kg];
#pragma unroll
    for (int i = 0; i < 4; ++i)
      bv[i] = *(const bf16x8*)&Bs[buf][((wc << 6) + (i << 4) + ln) * 32 + kg];
#pragma unroll
    for (int mi = 0; mi < 4; ++mi)
#pragma unroll
      for (int ni = 0; ni < 4; ++ni)
        acc[mi][ni] = __builtin_amdgcn_mfma_f32_16x16x32_bf16(
            av[mi], bv[ni], acc[mi][ni], 0, 0, 0);
    __syncthreads();
    buf ^= 1;
  }
#undef STAGE

  const int lh = lane >> 4;
  const int row0 = rowBase + (wr << 6) + (lh << 2);
  const int col0 = colBase + (wc << 6) + ln;

  if (MODE == 0) {  // fp32 plain
    float* C = (float*)Cout;
#pragma unroll
    for (int mi = 0; mi < 4; ++mi)
#pragma unroll
      for (int ni = 0; ni < 4; ++ni) {
        const int col = col0 + (ni << 4);
#pragma unroll
        for (int r = 0; r < 4; ++r)
          C[(size_t)(row0 + (mi << 4) + r) * ldc + col] = acc[mi][ni][r];
      }
  } else if (MODE == 1) {  // bf16, bias + relu
    __bf16* C = (__bf16*)Cout;
#pragma unroll
    for (int mi = 0; mi < 4; ++mi)
#pragma unroll
      for (int ni = 0; ni < 4; ++ni) {
        const int col = col0 + (ni << 4);
        const float b = bias[col];
#pragma unroll
        for (int r = 0; r < 4; ++r) {
          float v = fmaxf(acc[mi][ni][r] + b, 0.f);
          C[(size_t)(row0 + (mi << 4) + r) * ldc + col] = (__bf16)v;
        }
      }
  } else if (MODE == 2) {  // fp32, bias, bounded cols
    float* C = (float*)Cout;
#pragma unroll
    for (int mi = 0; mi < 4; ++mi)
#pragma unroll
      for (int ni = 0; ni < 4; ++ni) {
        const int col = col0 + (ni << 4);
        if (col < Nreal) {
          const float b = bias[col];
#pragma unroll
          for (int r = 0; r < 4; ++r)
            C[(size_t)(row0 + (mi << 4) + r) * ldc + col] = acc[mi][ni][r] + b;
        }
      }
  } else if (MODE == 6) {  // highway combine
    __bf16* C = (__bf16*)Cout;
#pragma unroll
    for (int mi = 0; mi < 4; ++mi)
#pragma unroll
      for (int ni = 0; ni < 4; ++ni) {
        const int col = col0 + (ni << 4);
#pragma unroll
        for (int r = 0; r < 4; ++r) {
          const int row = row0 + (mi << 4) + r;
          float xp = auxr[(size_t)row * 1024 + col];
          float hwl = auxr[(size_t)row * 1024 + 512 + col];
          float gn = sigmoidf_(acc[mi][ni][r] + xp + bias[col]);
          float hn = (float)hsrc[(size_t)row * 512 + col];
          C[(size_t)row * ldc + col] = (__bf16)(gn * hn + (1.f - gn) * hwl);
          hout[(size_t)row * hld + hoff + col] = (__bf16)hn;  // h0 -> xh
        }
      }
  }
}

// ---------------------------------------------------------------------------
// pack_all: all 9 per-slot weight-pack regions in ONE launch (r9: 63 small
// launches cost ~200us of overhead). Flat index -> region dispatch.
// Gate-perm map: dst row r <- src row ((r>>4)&3)*512 + ((r>>6)<<4) + (r&15).
// ---------------------------------------------------------------------------
#define PR0 2621440   // W_ih0 perm 2048x1280 -> WA[:,0:1280]
#define PR1 3670016   // + W_hh0 perm 2048x512 -> WA[:,1280:1792]
#define PR2 4325376   // + hwN_W0 x 512x1280 -> WX rows 0:512
#define PR3 4980736   // + hwL_W0 512x1280 -> WX rows 512:1024
#define PR4 5242880   // + hwN_W0 h 512x512 -> WH
#define PR5 6291456   // + W_ih1 perm 2048x512 -> WB[:,0:512]
#define PR6 7340032   // + W_hh1 perm 2048x512 -> WB[:,512:1024]
#define PR7 7471104   // + sh_W 256x512 -> WS
#define PR8 7503872   // + pred_W 128x256 (pad rows 100+) -> WP
__global__ void pack_all(const float* __restrict__ W_ih0, const float* __restrict__ W_hh0,
                         const float* __restrict__ hwN_W0, const float* __restrict__ hwL_W0,
                         const float* __restrict__ W_ih1, const float* __restrict__ W_hh1,
                         const float* __restrict__ sh_W, const float* __restrict__ pred_W,
                         __bf16* __restrict__ WA, __bf16* __restrict__ WX,
                         __bf16* __restrict__ WH, __bf16* __restrict__ WB,
                         __bf16* __restrict__ WS, __bf16* __restrict__ WP, int s) {
  const int idx = blockIdx.x * 256 + threadIdx.x;
  if (idx >= PR8) return;
  if (idx < PR0) {
    int i = idx, r = i / 1280, c = i - r * 1280;
    int sr = (((r >> 4) & 3) << 9) + ((r >> 6) << 4) + (r & 15);
    WA[(long)r * 1792 + c] = (__bf16)W_ih0[(size_t)s * 2048 * 1280 + (long)sr * 1280 + c];
  } else if (idx < PR1) {
    int i = idx - PR0, r = i >> 9, c = i & 511;
    int sr = (((r >> 4) & 3) << 9) + ((r >> 6) << 4) + (r & 15);
    WA[(long)r * 1792 + 1280 + c] = (__bf16)W_hh0[(size_t)s * 2048 * 512 + (long)sr * 512 + c];
  } else if (idx < PR2) {
    int i = idx - PR1, r = i / 1280, c = i - r * 1280;
    WX[(long)r * 1280 + c] = (__bf16)hwN_W0[(size_t)s * 512 * 1792 + (long)r * 1792 + c];
  } else if (idx < PR3) {
    int i = idx - PR2, r = i / 1280, c = i - r * 1280;
    WX[(long)(512 + r) * 1280 + c] = (__bf16)hwL_W0[(size_t)s * 512 * 1280 + (long)r * 1280 + c];
  } else if (idx < PR4) {
    int i = idx - PR3, r = i >> 9, c = i & 511;
    WH[(long)r * 512 + c] = (__bf16)hwN_W0[(size_t)s * 512 * 1792 + (long)r * 1792 + 1280 + c];
  } else if (idx < PR5) {
    int i = idx - PR4, r = i >> 9, c = i & 511;
    int sr = (((r >> 4) & 3) << 9) + ((r >> 6) << 4) + (r & 15);
    WB[(long)r * 1024 + c] = (__bf16)W_ih1[(size_t)s * 2048 * 512 + (long)sr * 512 + c];
  } else if (idx < PR6) {
    int i = idx - PR5, r = i >> 9, c = i & 511;
    int sr = (((r >> 4) & 3) << 9) + ((r >> 6) << 4) + (r & 15);
    WB[(long)r * 1024 + 512 + c] = (__bf16)W_hh1[(size_t)s * 2048 * 512 + (long)sr * 512 + c];
  } else if (idx < PR7) {
    int i = idx - PR6, r = i >> 9, c = i & 511;
    WS[(long)r * 512 + c] = (__bf16)sh_W[(size_t)s * 256 * 512 + (long)r * 512 + c];
  } else {
    int i = idx - PR7, r = i >> 8, c = i & 255;
    float v = (r < 100) ? pred_W[(size_t)s * 100 * 256 + (long)r * 256 + c] : 0.f;
    WP[(long)r * 256 + c] = (__bf16)v;
  }
}

__global__ void conv_inputs(const float* __restrict__ in, __bf16* __restrict__ xh) {
  int idx = blockIdx.x * 256 + threadIdx.x;  // B*1024
  int b = idx >> 10, c = idx & 1023;
  xh[(size_t)b * 1792 + c] = (__bf16)in[idx];
}

__global__ void set_start(const float* __restrict__ start, __bf16* __restrict__ xh) {
  int idx = blockIdx.x * 256 + threadIdx.x;  // B*256
  int b = idx >> 8, e = idx & 255;
  xh[(size_t)b * 1792 + 1024 + e] = (__bf16)start[e];
}

__global__ void emb_gather(const float* __restrict__ emb, const int* __restrict__ labels,
                           __bf16* __restrict__ xh) {
  int idx = blockIdx.x * 256 + threadIdx.x;  // B*256
  int b = idx >> 8, e = idx & 255;
  int lab = labels[b];
  xh[(size_t)b * 1792 + 1024 + e] = (__bf16)emb[(size_t)lab * 256 + e];
}

__global__ void zero_states(__bf16* __restrict__ xh, __bf16* __restrict__ xh1A) {
  int idx = blockIdx.x * 256 + threadIdx.x;  // B*512
  int b = idx >> 9, h = idx & 511;
  xh[(size_t)b * 1792 + 1280 + h] = (__bf16)0.f;   // h0 = 0
  xh1A[(size_t)b * 1024 + 512 + h] = (__bf16)0.f;  // h1 = 0 (buffer 0)
}

extern "C" void kernel_launch(void* const* d_in, const int* in_sizes, int n_in,
                              void* d_out, int out_size, void* d_ws, size_t ws_size,
                              hipStream_t stream) {
  const float* inputs = (const float*)d_in[0];
  const int* labels = (const int*)d_in[1];
  const float* start = (const float*)d_in[2];
  const float* emb = (const float*)d_in[3];
  const float* W_ih0 = (const float*)d_in[4];
  const float* W_hh0 = (const float*)d_in[5];
  const float* b_ih0 = (const float*)d_in[6];
  const float* b_hh0 = (const float*)d_in[7];
  const float* hwN_W0 = (const float*)d_in[8];
  const float* hwN_b0 = (const float*)d_in[9];
  const float* hwL_W0 = (const float*)d_in[10];
  const float* W_ih1 = (const float*)d_in[11];
  const float* W_hh1 = (const float*)d_in[12];
  const float* b_ih1 = (const float*)d_in[13];
  const float* b_hh1 = (const float*)d_in[14];
  // d_in[15..17]: hwN_W1 / hwN_b1 / hwL_W1 — dead in reference, skipped
  const float* sh_W = (const float*)d_in[18];
  const float* sh_b = (const float*)d_in[19];
  const float* pred_W = (const float*)d_in[20];
  const float* pred_b = (const float*)d_in[21];
  float* out = (float*)d_out;

  char* p = (char*)d_ws;
  size_t off = 0;
  auto alloc = [&](size_t bytes) {
    void* r = p + off;
    off += (bytes + 255) & ~(size_t)255;
    return r;
  };
  __bf16* WA = (__bf16*)alloc((size_t)2048 * 1792 * 2);  // [ih0|hh0 gate-perm]
  __bf16* WX = (__bf16*)alloc((size_t)1024 * 1280 * 2);  // [hwN-x ; hwL] K=1280
  __bf16* WH = (__bf16*)alloc((size_t)512 * 512 * 2);    // hwN h-part
  __bf16* WB = (__bf16*)alloc((size_t)2048 * 1024 * 2);  // [ih1|hh1 gate-perm]
  __bf16* WS = (__bf16*)alloc((size_t)256 * 512 * 2);    // sh_W
  __bf16* WP = (__bf16*)alloc((size_t)128 * 256 * 2);    // pred_W padded
  __bf16* xh = (__bf16*)alloc((size_t)BATCH * 1792 * 2);   // [inputs | emb | h0]
  __bf16* xh1A = (__bf16*)alloc((size_t)BATCH * 1024 * 2); // ping-pong [cur | h1]
  __bf16* xh1B = (__bf16*)alloc((size_t)BATCH * 1024 * 2);
  __bf16* h0new = (__bf16*)alloc((size_t)BATCH * 512 * 2);
  float* ghw = (float*)alloc((size_t)BATCH * 1024 * 4);  // [hwN-x | hwL] fp32
  float* c0 = (float*)alloc((size_t)BATCH * 512 * 4);
  float* c1 = (float*)alloc((size_t)BATCH * 512 * 4);
  __bf16* hidden = (__bf16*)ghw;  // aliases ghw (dead after hwy GEMM)
  (void)ws_size; (void)in_sizes; (void)n_in; (void)out_size;

  hipMemsetAsync(c0, 0, (size_t)BATCH * 512 * 4, stream);
  hipMemsetAsync(c1, 0, (size_t)BATCH * 512 * 4, stream);
  zero_states<<<BATCH * 512 / 256, 256, 0, stream>>>(xh, xh1A);
  conv_inputs<<<BATCH * 1024 / 256, 256, 0, stream>>>(inputs, xh);
  set_start<<<BATCH * 256 / 256, 256, 0, stream>>>(start, xh);

  const dim3 blk(256);
  for (int s = 0; s < SLOTS; ++s) {
    __bf16* xcur = (s & 1) ? xh1B : xh1A;
    __bf16* xnext = (s & 1) ? xh1A : xh1B;
    // pack this slot's weights: single launch, 9 regions
    pack_all<<<(PR8 + 255) / 256, blk, 0, stream>>>(
        W_ih0, W_hh0, hwN_W0, hwL_W0, W_ih1, W_hh1, sh_W, pred_W,
        WA, WX, WH, WB, WS, WP, s);

    // aux GEMM (2-phase, high occupancy): ghw = x[:,0:1280] @ WX^T (fp32)
    gemm_bt<0><<<dim3(8, 64), blk, 0, stream>>>(
        xh, 1792, WX, 1280, ghw, 1024, nullptr,
        nullptr, nullptr, 0, 0, nullptr, BATCH, 1024, 1280, 1024);
    // GEMM0 (1-barrier/tile, 256 blocks = exactly 1 round): fused LSTM-0
    gemm8p<<<256, 512, 131072, stream>>>(
        xh, 1792, WA, 1792, b_ih0 + s * 2048, b_hh0 + s * 2048,
        c0, h0new, 512, 0, 2048, 28);
    // hwy (MODE 6): acc = h0new @ WH^T; highway -> cur; h0new copied into xh
    gemm_bt<6><<<dim3(4, 64), blk, 0, stream>>>(
        h0new, 512, WH, 512, xcur, 1024, hwN_b0 + s * 512,
        ghw, xh, 1792, 1280, h0new, BATCH, 512, 512, 512);
    // teacher-forced embedding for next slot (aux+GEMM0 consumed current emb)
    if (s < SLOTS - 1)
      emb_gather<<<BATCH * 256 / 256, blk, 0, stream>>>(
          emb + (size_t)s * 100 * 256, labels + (size_t)s * BATCH, xh);
    // GEMM1 (256 blocks, 1 round): [cur|h1] @ WB^T -> fused LSTM-1
    gemm8p<<<256, 512, 131072, stream>>>(
        xcur, 1024, WB, 1024, b_ih1 + s * 2048, b_hh1 + s * 2048,
        c1, xnext, 1024, 512, 2048, 16);
    // sh (MODE 1): hidden = relu(h1 @ sh_W^T + sh_b) bf16
    gemm_bt<1><<<dim3(2, 64), blk, 0, stream>>>(
        xnext + 512, 1024, WS, 512, hidden, 256, sh_b + s * 256,
        nullptr, nullptr, 0, 0, nullptr, BATCH, 256, 512, 256);
    // pred (MODE 2): logits -> d_out[s]
    gemm_bt<2><<<dim3(1, 64), blk, 0, stream>>>(
        hidden, 256, WP, 256, out + (size_t)s * BATCH * 100, 100,
        pred_b + s * 100, nullptr, nullptr, 0, 0, nullptr, BATCH, 128, 256, 100);
  }
}